// Round 12
// baseline (1108.124 us; speedup 1.0000x reference)
//
#include <hip/hip_runtime.h>
#include <hip/hip_bf16.h>
#include <math.h>

#define B_ 32
#define T_ 128
#define V_ 32000
#define D_ 512
#define H_ 512

typedef __attribute__((ext_vector_type(8))) short bf16x8;
typedef __attribute__((ext_vector_type(8))) unsigned short u16x8;
typedef __attribute__((ext_vector_type(4))) float f32x4;
typedef __attribute__((ext_vector_type(2))) unsigned long long u64x2;

#define AS1 __attribute__((address_space(1)))
#define AS3 __attribute__((address_space(3)))

__device__ __forceinline__ unsigned short f2bf(float x) {
  unsigned int b = __float_as_uint(x);
  return (unsigned short)((b + 0x7FFFu + ((b >> 16) & 1u)) >> 16);
}
__device__ __forceinline__ float bf2f(unsigned short u) {
  return __uint_as_float(((unsigned int)u) << 16);
}
__device__ __forceinline__ float sigm(float x) { return 1.0f / (1.0f + __expf(-x)); }
__device__ __forceinline__ float tanh_fast(float x) { return 1.0f - 2.0f / (__expf(2.0f * x) + 1.0f); }

__device__ __forceinline__ unsigned long long ald64(const unsigned long long* p) {
  return __hip_atomic_load(p, __ATOMIC_RELAXED, __HIP_MEMORY_SCOPE_AGENT);
}
__device__ __forceinline__ unsigned ald32(const unsigned* p) {
  return __hip_atomic_load(p, __ATOMIC_RELAXED, __HIP_MEMORY_SCOPE_AGENT);
}

// ---------------- embedding gather -> bf16
__global__ __launch_bounds__(64) void embed_bf_kernel(const int* __restrict__ dst,
                                                      const float* __restrict__ E,
                                                      unsigned short* __restrict__ embbf) {
  int rt = blockIdx.x;           // t*32 + b
  int t = rt >> 5, b = rt & 31;
  int v = dst[b * T_ + t];
  const float4* src = (const float4*)(E + (size_t)v * D_);
  ushort4* d = (ushort4*)(embbf + (size_t)rt * D_);
  #pragma unroll
  for (int r = 0; r < 2; ++r) {
    float4 x = src[threadIdx.x + r * 64];
    ushort4 o; o.x = f2bf(x.x); o.y = f2bf(x.y); o.z = f2bf(x.z); o.w = f2bf(x.w);
    d[threadIdx.x + r * 64] = o;
  }
}

// ---------------- generic f32 -> bf16
__global__ void cvt_kernel(const float* __restrict__ in, unsigned short* __restrict__ out, int n4) {
  int stride = gridDim.x * blockDim.x;
  for (int i = blockIdx.x * blockDim.x + threadIdx.x; i < n4; i += stride) {
    float4 v = ((const float4*)in)[i];
    ushort4 o; o.x = f2bf(v.x); o.y = f2bf(v.y); o.z = f2bf(v.z); o.w = f2bf(v.w);
    ((ushort4*)out)[i] = o;
  }
}

// ---------------- W1bf[r][c] = bf16(Wih[r][c]), c<512 (row stride 1024)
__global__ void cvt_w1_kernel(const float* __restrict__ Wih, unsigned short* __restrict__ W1bf, int n4) {
  int stride = gridDim.x * blockDim.x;
  for (int i = blockIdx.x * blockDim.x + threadIdx.x; i < n4; i += stride) {
    int flat = i * 4;
    int r = flat >> 9, c = flat & 511;
    float4 v = *(const float4*)(Wih + (size_t)r * 1024 + c);
    ushort4 o; o.x = f2bf(v.x); o.y = f2bf(v.y); o.z = f2bf(v.z); o.w = f2bf(v.w);
    ((ushort4*)W1bf)[i] = o;
  }
}

// ---------------- Wr rows reordered for lane-local epilogue:
// out_row = bid*128 + k_loc*4 + gate  (gate = grow>>9, kg = grow&511)
// per-row 16B-chunk swizzle: chunk ^= (out_row & 7)
__global__ void wr_prep_swz_kernel(const float* __restrict__ Wih, const float* __restrict__ Whh,
                                   unsigned short* __restrict__ Wrs, int n4) {
  int stride = gridDim.x * blockDim.x;
  for (int i = blockIdx.x * blockDim.x + threadIdx.x; i < n4; i += stride) {
    int flat = i * 4;
    int grow = flat >> 9, k = flat & 511;
    float4 a = *(const float4*)(Wih + (size_t)grow * 1024 + 512 + k);
    float4 b = ((const float4*)Whh)[i];
    ushort4 o;
    o.x = f2bf(a.x + b.x); o.y = f2bf(a.y + b.y); o.z = f2bf(a.z + b.z); o.w = f2bf(a.w + b.w);
    int gate = grow >> 9, kgl = grow & 511;
    int orow = (kgl >> 5) * 128 + (kgl & 31) * 4 + gate;
    int chunk = (k >> 3) ^ (orow & 7);
    *(ushort4*)(Wrs + (size_t)orow * 512 + chunk * 8 + (k & 7)) = o;
  }
}

// ---------------- pre-GEMM: preA3[t][kg][b][gate] = bf16(emb . W1 + bias)
__global__ __launch_bounds__(256) void gemm_pre_kernel(
    const unsigned short* __restrict__ A,
    const unsigned short* __restrict__ Bm,
    const float* __restrict__ bih, const float* __restrict__ bhh,
    unsigned short* __restrict__ preA3)
{
  __shared__ unsigned short ldsA[2][128 * 32];
  __shared__ unsigned short ldsB[2][128 * 32];
  const int tid = threadIdx.x;
  const int lane = tid & 63;
  const int wid = tid >> 6;
  const int wm = wid >> 1, wn = wid & 1;
  const int m0 = blockIdx.y * 128;
  const int n0 = blockIdx.x * 128;
  const int srow = lane >> 2;
  const int scol = (lane & 3) * 8;

  f32x4 acc[4][4] = {};
  const int NK = 512 / 32;

  auto stage = [&](int kk, int buf) {
    const int k0 = kk * 32;
    #pragma unroll
    for (int c = 0; c < 2; ++c) {
      const int r = wid * 32 + c * 16;
      const unsigned short* sa = A  + (size_t)(m0 + r + srow) * 512 + k0 + scol;
      const unsigned short* sb = Bm + (size_t)(n0 + r + srow) * 512 + k0 + scol;
      __builtin_amdgcn_global_load_lds((const AS1 void*)sa, (AS3 void*)&ldsA[buf][r * 32], 16, 0, 0);
      __builtin_amdgcn_global_load_lds((const AS1 void*)sb, (AS3 void*)&ldsB[buf][r * 32], 16, 0, 0);
    }
  };

  stage(0, 0);
  __syncthreads();

  const int rl = lane & 15;
  const int kb = lane >> 4;

  for (int kk = 0; kk < NK; ++kk) {
    const int buf = kk & 1;
    if (kk + 1 < NK) stage(kk + 1, buf ^ 1);
    const bf16x8* Af = (const bf16x8*)&ldsA[buf][0];
    const bf16x8* Bf = (const bf16x8*)&ldsB[buf][0];
    bf16x8 av[4], bv[4];
    #pragma unroll
    for (int mi = 0; mi < 4; ++mi) av[mi] = Af[(wm * 64 + mi * 16 + rl) * 4 + kb];
    #pragma unroll
    for (int ni = 0; ni < 4; ++ni) bv[ni] = Bf[(wn * 64 + ni * 16 + rl) * 4 + kb];
    #pragma unroll
    for (int mi = 0; mi < 4; ++mi)
      #pragma unroll
      for (int ni = 0; ni < 4; ++ni)
        acc[mi][ni] = __builtin_amdgcn_mfma_f32_16x16x32_bf16(av[mi], bv[ni], acc[mi][ni], 0, 0, 0);
    __syncthreads();
  }

  const int rb = (lane >> 4) * 4;
  #pragma unroll
  for (int mi = 0; mi < 4; ++mi)
    #pragma unroll
    for (int ni = 0; ni < 4; ++ni) {
      int mbase = m0 + wm * 64 + mi * 16 + rb;
      int col   = n0 + wn * 64 + ni * 16 + rl;
      int gate = col >> 9, kg = col & 511;
      int tt = mbase >> 5, bb0 = mbase & 31;
      float bb = bih[col] + bhh[col];
      #pragma unroll
      for (int j = 0; j < 4; ++j)
        preA3[(((size_t)tt * 512 + kg) * 32 + bb0 + j) * 4 + gate] = f2bf(acc[mi][ni][j] + bb);
    }
}

// ---------------- preA3[t=0][kg][:][gate] += (out0 - h0) @ W2^T  (row r = grow)
__global__ __launch_bounds__(256) void delta0_kernel(const float* __restrict__ Wih,
                                                     const float* __restrict__ out0,
                                                     const float* __restrict__ h0,
                                                     unsigned short* __restrict__ preA3) {
  const int r = blockIdx.x;
  const int tid = threadIdx.x;
  const int b = tid >> 3, seg = tid & 7;
  __shared__ float red[32][9];
  const float4* o4 = (const float4*)(out0 + (size_t)b * 512 + seg * 64);
  const float4* h4 = (const float4*)(h0 + (size_t)b * 512 + seg * 64);
  const float4* w4 = (const float4*)(Wih + (size_t)r * 1024 + 512 + seg * 64);
  float s = 0.f;
  #pragma unroll
  for (int j = 0; j < 16; ++j) {
    float4 o = o4[j], h = h4[j], w = w4[j];
    s += (o.x - h.x) * w.x + (o.y - h.y) * w.y + (o.z - h.z) * w.z + (o.w - h.w) * w.w;
  }
  red[b][seg] = s;
  __syncthreads();
  if (tid < 32) {
    float t = 0.f;
    #pragma unroll
    for (int j = 0; j < 8; ++j) t += red[tid][j];
    int gate = r >> 9, kgl = r & 511;
    unsigned short* p = preA3 + ((size_t)kgl * 32 + tid) * 4 + gate;
    *p = f2bf(bf2f(*p) + t);
  }
}

// ---------------- persistent LSTM, 16 blocks x 1024 threads, ROLE-SPLIT phases.
// (unchanged from R11 - proven 501 us)
__global__ __launch_bounds__(1024) void lstm_persist_rs_kernel(
    const unsigned short* __restrict__ Wrs,   // [2048][512] reordered+swizzled bf16
    const unsigned short* __restrict__ preA3, // [T][512][32][4] bf16 (bias folded)
    const float* __restrict__ c0,             // [32][512] f32
    unsigned short* __restrict__ hb0,         // [32][512] bf16 (h0 at entry)
    unsigned short* __restrict__ hb1,         // pong
    unsigned short* __restrict__ Abf,         // [B*T][512] bf16
    unsigned int* __restrict__ flags)         // [2][16] x 64B lines, zeroed each call
{
  __shared__ unsigned short wlds[128 * 512];            // 128 KB, resident
  __shared__ __align__(16) char hexch[2][16 * 1024];    // 2 x 16 KB half-batch h tiles
  const int tid = threadIdx.x, bid = blockIdx.x;
  const int lane = tid & 63, wid = tid >> 6;

  #pragma unroll
  for (int it = 0; it < 8; ++it) {
    int r = it * 16 + wid;
    const unsigned short* src = Wrs + ((size_t)bid * 128 + r) * 512 + lane * 8;
    __builtin_amdgcn_global_load_lds((const AS1 void*)src, (AS3 void*)&wlds[r * 512], 16, 0, 0);
  }

  const int myhalf = wid >> 3;
  const int rt = wid & 7;
  const int q = lane >> 4, rl = lane & 15;
  const int kg = bid * 32 + rt * 4 + q;
  const int b = myhalf * 16 + rl;
  float c_reg = c0[(size_t)b * 512 + kg];

  const int row = rt * 16 + rl;
  const char* wbase = (const char*)wlds + row * 1024;
  const int rx = (row & 7) << 4;
  const int hx = (rl & 7) << 4;

  const int sw = wid & 7;
  const int sr = sw * 2 + (lane >> 5);
  const int sc = lane & 31;
  const int sblk = sc >> 1;
  const int srx = (sr & 7) << 4;
  const int sofs = sc * 32;

  if (myhalf == 0) {
    const unsigned long long* src =
        (const unsigned long long*)(hb0 + (size_t)sr * 512) + sc * 4;
    unsigned long long d0 = ald64(src + 0), d1 = ald64(src + 1);
    unsigned long long d2 = ald64(src + 2), d3 = ald64(src + 3);
    char* dst = hexch[0] + sr * 1024;
    u64x2 w0; w0[0] = d0; w0[1] = d1;
    u64x2 w1; w1[0] = d2; w1[1] = d3;
    *(u64x2*)(dst + (sofs ^ srx)) = w0;
    *(u64x2*)(dst + ((sofs + 16) ^ srx)) = w1;
  }
  __syncthreads();

  for (int p = 0; p < 2 * T_; ++p) {
    const int t = p >> 1, ph = p & 1, buf = p & 1;

    if (myhalf == ph) {
      unsigned long long pre =
          *(const unsigned long long*)(preA3 + (((size_t)t * 512 + kg) * 32 + b) * 4);
      const char* hbase = hexch[buf] + rl * 1024;
      f32x4 acc = {}, acc2 = {};
      #pragma unroll
      for (int kk = 0; kk < 16; kk += 2) {
        int k0 = kk * 32 + q * 8;
        int k1 = k0 + 32;
        bf16x8 av0 = *(const bf16x8*)(wbase + ((k0 * 2) ^ rx));
        bf16x8 bv0 = *(const bf16x8*)(hbase + ((k0 * 2) ^ hx));
        bf16x8 av1 = *(const bf16x8*)(wbase + ((k1 * 2) ^ rx));
        bf16x8 bv1 = *(const bf16x8*)(hbase + ((k1 * 2) ^ hx));
        acc  = __builtin_amdgcn_mfma_f32_16x16x32_bf16(av0, bv0, acc, 0, 0, 0);
        acc2 = __builtin_amdgcn_mfma_f32_16x16x32_bf16(av1, bv1, acc2, 0, 0, 0);
      }
      float g0 = acc[0] + acc2[0] + bf2f((unsigned short)(pre));
      float g1 = acc[1] + acc2[1] + bf2f((unsigned short)(pre >> 16));
      float g2 = acc[2] + acc2[2] + bf2f((unsigned short)(pre >> 32));
      float g3 = acc[3] + acc2[3] + bf2f((unsigned short)(pre >> 48));
      float iv = sigm(g0), fv = sigm(g1), gv = tanh_fast(g2), ov = sigm(g3);
      float cn = fv * c_reg + iv * gv;
      c_reg = cn;
      float hn = ov * tanh_fast(cn);
      int hv = (int)f2bf(hn);
      int nb = __shfl(hv, lane + 16);
      if ((q & 1) == 0) {
        unsigned pair = (unsigned)hv | ((unsigned)nb << 16);
        if (t != T_ - 1) {
          unsigned short* hout = ((t + 1) & 1) ? hb1 : hb0;
          __hip_atomic_store((unsigned int*)(hout + (size_t)b * 512 + kg), pair,
                             __ATOMIC_RELAXED, __HIP_MEMORY_SCOPE_AGENT);
        }
        *(unsigned*)(Abf + ((size_t)b * T_ + t) * 512 + kg) = pair;
      }
    } else if (p + 1 < 2 * T_) {
      const int t2 = (p + 1) >> 1;
      if (t2 > 0) {
        const unsigned* fl = &flags[(myhalf * 16 + sblk) * 16];
        unsigned spins = 0;
        while (ald32(fl) < (unsigned)t2) {
          if (++spins > 1000000u) break;
        }
      }
      const unsigned short* hsrc = (t2 & 1) ? hb1 : hb0;
      const unsigned long long* src =
          (const unsigned long long*)(hsrc + (size_t)(myhalf * 16 + sr) * 512) + sc * 4;
      unsigned long long d0 = ald64(src + 0), d1 = ald64(src + 1);
      unsigned long long d2 = ald64(src + 2), d3 = ald64(src + 3);
      char* dst = hexch[buf ^ 1] + sr * 1024;
      u64x2 w0; w0[0] = d0; w0[1] = d1;
      u64x2 w1; w1[0] = d2; w1[1] = d3;
      *(u64x2*)(dst + (sofs ^ srx)) = w0;
      *(u64x2*)(dst + ((sofs + 16) ^ srx)) = w1;
    }

    __syncthreads();

    if (tid == ph * 512)
      __hip_atomic_store(&flags[(ph * 16 + bid) * 16], (unsigned)(t + 1),
                         __ATOMIC_RELAXED, __HIP_MEMORY_SCOPE_AGENT);
  }
}

// ---------------- projection GEMM (swizzled LDS) + softmax partials
// use_bf=1: write bf16 C to Cbf; use_bf=0: write f32 C (fallback).
__global__ __launch_bounds__(256) void gemm_kernel(
    const unsigned short* __restrict__ A,
    const unsigned short* __restrict__ Bm,
    float* __restrict__ C,
    unsigned short* __restrict__ Cbf,
    int use_bf,
    float* __restrict__ pmax, float* __restrict__ psum)
{
  __shared__ unsigned short ldsA[2][128 * 32];
  __shared__ unsigned short ldsB[2][128 * 32];
  __shared__ float smax[2][128];
  __shared__ float ssum[2][128];
  const int tid = threadIdx.x;
  const int lane = tid & 63;
  const int wid = tid >> 6;
  const int wm = wid >> 1, wn = wid & 1;
  const int m0 = blockIdx.x * 128;
  const int n0 = blockIdx.y * 128;
  const int srow = lane >> 2;

  f32x4 acc[4][4] = {};
  const int NK = 512 / 32;

  auto stage = [&](int kk, int buf) {
    const int k0 = kk * 32;
    const int sw = (srow >> 1) & 3;
    const int gc = ((lane & 3) ^ sw) * 8;
    #pragma unroll
    for (int c = 0; c < 2; ++c) {
      const int r = wid * 32 + c * 16;
      const unsigned short* sa = A  + (size_t)(m0 + r + srow) * 512 + k0 + gc;
      const unsigned short* sb = Bm + (size_t)(n0 + r + srow) * 512 + k0 + gc;
      __builtin_amdgcn_global_load_lds((const AS1 void*)sa, (AS3 void*)&ldsA[buf][r * 32], 16, 0, 0);
      __builtin_amdgcn_global_load_lds((const AS1 void*)sb, (AS3 void*)&ldsB[buf][r * 32], 16, 0, 0);
    }
  };

  stage(0, 0);
  __syncthreads();

  const int rl = lane & 15;
  const int kb = lane >> 4;
  const int rsw = kb ^ ((rl >> 1) & 3);

  for (int kk = 0; kk < NK; ++kk) {
    const int buf = kk & 1;
    if (kk + 1 < NK) stage(kk + 1, buf ^ 1);
    const bf16x8* Af = (const bf16x8*)&ldsA[buf][0];
    const bf16x8* Bf = (const bf16x8*)&ldsB[buf][0];
    bf16x8 av[4], bv[4];
    #pragma unroll
    for (int mi = 0; mi < 4; ++mi) av[mi] = Af[(wm * 64 + mi * 16 + rl) * 4 + rsw];
    #pragma unroll
    for (int ni = 0; ni < 4; ++ni) bv[ni] = Bf[(wn * 64 + ni * 16 + rl) * 4 + rsw];
    #pragma unroll
    for (int mi = 0; mi < 4; ++mi)
      #pragma unroll
      for (int ni = 0; ni < 4; ++ni)
        acc[mi][ni] = __builtin_amdgcn_mfma_f32_16x16x32_bf16(av[mi], bv[ni], acc[mi][ni], 0, 0, 0);
    __syncthreads();
  }

  const int rb = kb * 4;
  if (use_bf) {
    #pragma unroll
    for (int mi = 0; mi < 4; ++mi)
      #pragma unroll
      for (int ni = 0; ni < 4; ++ni) {
        size_t rrow = (size_t)(m0 + wm * 64 + mi * 16 + rb);
        size_t col = (size_t)(n0 + wn * 64 + ni * 16 + rl);
        #pragma unroll
        for (int j = 0; j < 4; ++j)
          __builtin_nontemporal_store(f2bf(acc[mi][ni][j]), &Cbf[(rrow + j) * (size_t)V_ + col]);
      }
  } else {
    #pragma unroll
    for (int mi = 0; mi < 4; ++mi)
      #pragma unroll
      for (int ni = 0; ni < 4; ++ni) {
        size_t rrow = (size_t)(m0 + wm * 64 + mi * 16 + rb);
        size_t col = (size_t)(n0 + wn * 64 + ni * 16 + rl);
        #pragma unroll
        for (int j = 0; j < 4; ++j)
          __builtin_nontemporal_store(acc[mi][ni][j], &C[(rrow + j) * (size_t)V_ + col]);
      }
  }

  // ---- per-tile row max / sum-exp partials ----
  float tm[4][4];
  #pragma unroll
  for (int mi = 0; mi < 4; ++mi)
    #pragma unroll
    for (int j = 0; j < 4; ++j) {
      float m = fmaxf(fmaxf(acc[mi][0][j], acc[mi][1][j]), fmaxf(acc[mi][2][j], acc[mi][3][j]));
      m = fmaxf(m, __shfl_xor(m, 1)); m = fmaxf(m, __shfl_xor(m, 2));
      m = fmaxf(m, __shfl_xor(m, 4)); m = fmaxf(m, __shfl_xor(m, 8));
      tm[mi][j] = m;
    }
  if (rl == 0) {
    #pragma unroll
    for (int mi = 0; mi < 4; ++mi)
      #pragma unroll
      for (int j = 0; j < 4; ++j)
        smax[wn][wm * 64 + mi * 16 + kb * 4 + j] = tm[mi][j];
  }
  __syncthreads();
  float ts[4][4];
  #pragma unroll
  for (int mi = 0; mi < 4; ++mi)
    #pragma unroll
    for (int j = 0; j < 4; ++j) {
      int rlocal = wm * 64 + mi * 16 + kb * 4 + j;
      float M = fmaxf(smax[0][rlocal], smax[1][rlocal]);
      float s = __expf(acc[mi][0][j] - M) + __expf(acc[mi][1][j] - M) +
                __expf(acc[mi][2][j] - M) + __expf(acc[mi][3][j] - M);
      s += __shfl_xor(s, 1); s += __shfl_xor(s, 2);
      s += __shfl_xor(s, 4); s += __shfl_xor(s, 8);
      ts[mi][j] = s;
    }
  if (rl == 0) {
    #pragma unroll
    for (int mi = 0; mi < 4; ++mi)
      #pragma unroll
      for (int j = 0; j < 4; ++j)
        ssum[wn][wm * 64 + mi * 16 + kb * 4 + j] = ts[mi][j];
  }
  __syncthreads();
  if (tid < 128) {
    float M = fmaxf(smax[0][tid], smax[1][tid]);
    float S = ssum[0][tid] + ssum[1][tid];
    pmax[(size_t)(m0 + tid) * 256 + blockIdx.y] = M;
    psum[(size_t)(m0 + tid) * 256 + blockIdx.y] = S;
  }
}

__device__ __forceinline__ float lse_from_partials(const float* pmax, const float* psum,
                                                   size_t row, int tid, int lane, int wid,
                                                   float* red) {
  float pm = (tid < 250) ? pmax[row * 256 + tid] : -INFINITY;
  float ps = (tid < 250) ? psum[row * 256 + tid] : 0.f;

  float m = pm;
  #pragma unroll
  for (int off = 32; off > 0; off >>= 1) m = fmaxf(m, __shfl_xor(m, off));
  if (lane == 0) red[wid] = m;
  __syncthreads();
  m = fmaxf(fmaxf(red[0], red[1]), fmaxf(red[2], red[3]));
  __syncthreads();

  float s = (tid < 250) ? ps * __expf(pm - m) : 0.f;
  #pragma unroll
  for (int off = 32; off > 0; off >>= 1) s += __shfl_xor(s, off);
  if (lane == 0) red[wid] = s;
  __syncthreads();
  s = red[0] + red[1] + red[2] + red[3];
  return m + logf(s);
}

// ---------------- finish (bf16 path): C[row] = bf2f(Cbf[row]) - lse
__global__ __launch_bounds__(256) void softmax_finish_bf_kernel(
    const unsigned short* __restrict__ Cbf, float* __restrict__ C,
    const float* __restrict__ pmax, const float* __restrict__ psum) {
  const size_t row = blockIdx.x;
  const int tid = threadIdx.x, lane = tid & 63, wid = tid >> 6;
  __shared__ float red[4];
  const float lse = lse_from_partials(pmax, psum, row, tid, lane, wid, red);

  const u16x8* pb = (const u16x8*)(Cbf + row * (size_t)V_);
  f32x4* pf = (f32x4*)(C + row * (size_t)V_);
  for (int i = tid; i < 4000; i += 256) {     // 4000 x 8 ushorts = 32000
    u16x8 v = __builtin_nontemporal_load(&pb[i]);
    f32x4 lo, hi;
    lo[0] = bf2f(v[0]) - lse; lo[1] = bf2f(v[1]) - lse;
    lo[2] = bf2f(v[2]) - lse; lo[3] = bf2f(v[3]) - lse;
    hi[0] = bf2f(v[4]) - lse; hi[1] = bf2f(v[5]) - lse;
    hi[2] = bf2f(v[6]) - lse; hi[3] = bf2f(v[7]) - lse;
    __builtin_nontemporal_store(lo, &pf[i * 2]);
    __builtin_nontemporal_store(hi, &pf[i * 2 + 1]);
  }
}

// ---------------- finish (f32 fallback): C[row] -= lse in place
__global__ __launch_bounds__(256) void softmax_finish_kernel(
    float* __restrict__ C, const float* __restrict__ pmax, const float* __restrict__ psum) {
  const size_t row = blockIdx.x;
  const int tid = threadIdx.x, lane = tid & 63, wid = tid >> 6;
  __shared__ float red[4];
  const float lse = lse_from_partials(pmax, psum, row, tid, lane, wid, red);

  f32x4* p4 = (f32x4*)(C + row * (size_t)V_);
  for (int i = tid; i < 8000; i += 256) {
    f32x4 v = p4[i];
    v -= lse;
    __builtin_nontemporal_store(v, &p4[i]);
  }
}

extern "C" void kernel_launch(void* const* d_in, const int* in_sizes, int n_in,
                              void* d_out, int out_size, void* d_ws, size_t ws_size,
                              hipStream_t stream) {
  const int*   dst  = (const int*)d_in[0];
  const float* E    = (const float*)d_in[1];
  const float* Wih  = (const float*)d_in[2];
  const float* Whh  = (const float*)d_in[3];
  const float* bih  = (const float*)d_in[4];
  const float* bhh  = (const float*)d_in[5];
  const float* h0   = (const float*)d_in[6];
  const float* c0   = (const float*)d_in[7];
  const float* out0 = (const float*)d_in[8];
  float* C = (float*)d_out;

  char* ws = (char*)d_ws;
  unsigned short* Ebf   = (unsigned short*)(ws);                      // 32.77 MB
  unsigned short* preA3 = (unsigned short*)(ws + (size_t)33554432);   // 16.78 MB
  unsigned short* Wrs   = (unsigned short*)(ws + (size_t)50331648);   // 2.10 MB
  unsigned short* embbf = (unsigned short*)(ws + (size_t)52428800);   // pre-phase
  float*          pmax  = (float*)(ws + (size_t)52428800);            // post-phase 4.19 MB
  unsigned short* W1bf  = (unsigned short*)(ws + (size_t)56623104);   // pre-phase
  float*          psum  = (float*)(ws + (size_t)56623104);            // post-phase 4.19 MB
  unsigned short* Abf   = (unsigned short*)(ws + (size_t)60817408);   // 4.19 MB
  unsigned short* hb0   = (unsigned short*)(ws + (size_t)65011712);   // 32 KB
  unsigned short* hb1   = (unsigned short*)(ws + (size_t)65044480);   // 32 KB
  unsigned int*   flg   = (unsigned int*)(ws + (size_t)65077248);     // 2 KB (2 x 16 x 64B)
  unsigned short* Cbf   = (unsigned short*)(ws + (size_t)65079296);   // 262.1 MB (optional)

  const int use_bf = (ws_size >= (size_t)65079296 + (size_t)B_ * T_ * V_ * 2) ? 1 : 0;

  (void)hipMemsetAsync(flg, 0, 2048, stream);

  // --- precompute ---
  embed_bf_kernel<<<dim3(T_ * B_), dim3(64), 0, stream>>>(dst, E, embbf);
  cvt_kernel<<<dim3(2048), dim3(256), 0, stream>>>(E, Ebf, V_ * D_ / 4);
  cvt_w1_kernel<<<dim3(256), dim3(256), 0, stream>>>(Wih, W1bf, 2048 * 512 / 4);
  wr_prep_swz_kernel<<<dim3(256), dim3(256), 0, stream>>>(Wih, Whh, Wrs, 2048 * 512 / 4);

  gemm_pre_kernel<<<dim3(2048 / 128, 4096 / 128), dim3(256), 0, stream>>>(embbf, W1bf, bih, bhh, preA3);
  delta0_kernel<<<dim3(2048), dim3(256), 0, stream>>>(Wih, out0, h0, preA3);
  cvt_kernel<<<dim3(16), dim3(256), 0, stream>>>(h0, hb0, B_ * H_ / 4);

  // --- full recurrence, one launch, 16 blocks, role-split phases ---
  lstm_persist_rs_kernel<<<dim3(16), dim3(1024), 0, stream>>>(Wrs, preA3, c0, hb0, hb1, Abf, flg);

  // --- projection + fused softmax partials ---
  gemm_kernel<<<dim3(32, 250), dim3(256), 0, stream>>>(Abf, Ebf, C, Cbf, use_bf, pmax, psum);
  if (use_bf)
    softmax_finish_bf_kernel<<<dim3(B_ * T_), dim3(256), 0, stream>>>(Cbf, C, pmax, psum);
  else
    softmax_finish_kernel<<<dim3(B_ * T_), dim3(256), 0, stream>>>(C, pmax, psum);
}

// Round 13
// 1103.975 us; speedup vs baseline: 1.0038x; 1.0038x over previous
//
#include <hip/hip_runtime.h>
#include <hip/hip_bf16.h>
#include <math.h>

#define B_ 32
#define T_ 128
#define V_ 32000
#define D_ 512
#define H_ 512

typedef __attribute__((ext_vector_type(8))) short bf16x8;
typedef __attribute__((ext_vector_type(8))) unsigned short u16x8;
typedef __attribute__((ext_vector_type(4))) float f32x4;
typedef __attribute__((ext_vector_type(2))) unsigned long long u64x2;

#define AS1 __attribute__((address_space(1)))
#define AS3 __attribute__((address_space(3)))

__device__ __forceinline__ unsigned short f2bf(float x) {
  unsigned int b = __float_as_uint(x);
  return (unsigned short)((b + 0x7FFFu + ((b >> 16) & 1u)) >> 16);
}
__device__ __forceinline__ float bf2f(unsigned short u) {
  return __uint_as_float(((unsigned int)u) << 16);
}
__device__ __forceinline__ float sigm(float x) { return 1.0f / (1.0f + __expf(-x)); }
__device__ __forceinline__ float tanh_fast(float x) { return 1.0f - 2.0f / (__expf(2.0f * x) + 1.0f); }

__device__ __forceinline__ unsigned long long ald64(const unsigned long long* p) {
  return __hip_atomic_load(p, __ATOMIC_RELAXED, __HIP_MEMORY_SCOPE_AGENT);
}
__device__ __forceinline__ unsigned ald32(const unsigned* p) {
  return __hip_atomic_load(p, __ATOMIC_RELAXED, __HIP_MEMORY_SCOPE_AGENT);
}

// ---------------- embedding gather -> bf16
__global__ __launch_bounds__(64) void embed_bf_kernel(const int* __restrict__ dst,
                                                      const float* __restrict__ E,
                                                      unsigned short* __restrict__ embbf) {
  int rt = blockIdx.x;           // t*32 + b
  int t = rt >> 5, b = rt & 31;
  int v = dst[b * T_ + t];
  const float4* src = (const float4*)(E + (size_t)v * D_);
  ushort4* d = (ushort4*)(embbf + (size_t)rt * D_);
  #pragma unroll
  for (int r = 0; r < 2; ++r) {
    float4 x = src[threadIdx.x + r * 64];
    ushort4 o; o.x = f2bf(x.x); o.y = f2bf(x.y); o.z = f2bf(x.z); o.w = f2bf(x.w);
    d[threadIdx.x + r * 64] = o;
  }
}

// ---------------- generic f32 -> bf16
__global__ void cvt_kernel(const float* __restrict__ in, unsigned short* __restrict__ out, int n4) {
  int stride = gridDim.x * blockDim.x;
  for (int i = blockIdx.x * blockDim.x + threadIdx.x; i < n4; i += stride) {
    float4 v = ((const float4*)in)[i];
    ushort4 o; o.x = f2bf(v.x); o.y = f2bf(v.y); o.z = f2bf(v.z); o.w = f2bf(v.w);
    ((ushort4*)out)[i] = o;
  }
}

// ---------------- W1bf[r][c] = bf16(Wih[r][c]), c<512 (row stride 1024)
__global__ void cvt_w1_kernel(const float* __restrict__ Wih, unsigned short* __restrict__ W1bf, int n4) {
  int stride = gridDim.x * blockDim.x;
  for (int i = blockIdx.x * blockDim.x + threadIdx.x; i < n4; i += stride) {
    int flat = i * 4;
    int r = flat >> 9, c = flat & 511;
    float4 v = *(const float4*)(Wih + (size_t)r * 1024 + c);
    ushort4 o; o.x = f2bf(v.x); o.y = f2bf(v.y); o.z = f2bf(v.z); o.w = f2bf(v.w);
    ((ushort4*)W1bf)[i] = o;
  }
}

// ---------------- Wr rows reordered for lane-local epilogue:
// out_row = bid*128 + k_loc*4 + gate  (gate = grow>>9, kg = grow&511)
// per-row 16B-chunk swizzle: chunk ^= (out_row & 7)
__global__ void wr_prep_swz_kernel(const float* __restrict__ Wih, const float* __restrict__ Whh,
                                   unsigned short* __restrict__ Wrs, int n4) {
  int stride = gridDim.x * blockDim.x;
  for (int i = blockIdx.x * blockDim.x + threadIdx.x; i < n4; i += stride) {
    int flat = i * 4;
    int grow = flat >> 9, k = flat & 511;
    float4 a = *(const float4*)(Wih + (size_t)grow * 1024 + 512 + k);
    float4 b = ((const float4*)Whh)[i];
    ushort4 o;
    o.x = f2bf(a.x + b.x); o.y = f2bf(a.y + b.y); o.z = f2bf(a.z + b.z); o.w = f2bf(a.w + b.w);
    int gate = grow >> 9, kgl = grow & 511;
    int orow = (kgl >> 5) * 128 + (kgl & 31) * 4 + gate;
    int chunk = (k >> 3) ^ (orow & 7);
    *(ushort4*)(Wrs + (size_t)orow * 512 + chunk * 8 + (k & 7)) = o;
  }
}

// ---------------- pre-GEMM: preA3[t][kg][b][gate] = bf16(emb . W1 + bias)
__global__ __launch_bounds__(256) void gemm_pre_kernel(
    const unsigned short* __restrict__ A,
    const unsigned short* __restrict__ Bm,
    const float* __restrict__ bih, const float* __restrict__ bhh,
    unsigned short* __restrict__ preA3)
{
  __shared__ unsigned short ldsA[2][128 * 32];
  __shared__ unsigned short ldsB[2][128 * 32];
  const int tid = threadIdx.x;
  const int lane = tid & 63;
  const int wid = tid >> 6;
  const int wm = wid >> 1, wn = wid & 1;
  const int m0 = blockIdx.y * 128;
  const int n0 = blockIdx.x * 128;
  const int srow = lane >> 2;
  const int scol = (lane & 3) * 8;

  f32x4 acc[4][4] = {};
  const int NK = 512 / 32;

  auto stage = [&](int kk, int buf) {
    const int k0 = kk * 32;
    #pragma unroll
    for (int c = 0; c < 2; ++c) {
      const int r = wid * 32 + c * 16;
      const unsigned short* sa = A  + (size_t)(m0 + r + srow) * 512 + k0 + scol;
      const unsigned short* sb = Bm + (size_t)(n0 + r + srow) * 512 + k0 + scol;
      __builtin_amdgcn_global_load_lds((const AS1 void*)sa, (AS3 void*)&ldsA[buf][r * 32], 16, 0, 0);
      __builtin_amdgcn_global_load_lds((const AS1 void*)sb, (AS3 void*)&ldsB[buf][r * 32], 16, 0, 0);
    }
  };

  stage(0, 0);
  __syncthreads();

  const int rl = lane & 15;
  const int kb = lane >> 4;

  for (int kk = 0; kk < NK; ++kk) {
    const int buf = kk & 1;
    if (kk + 1 < NK) stage(kk + 1, buf ^ 1);
    const bf16x8* Af = (const bf16x8*)&ldsA[buf][0];
    const bf16x8* Bf = (const bf16x8*)&ldsB[buf][0];
    bf16x8 av[4], bv[4];
    #pragma unroll
    for (int mi = 0; mi < 4; ++mi) av[mi] = Af[(wm * 64 + mi * 16 + rl) * 4 + kb];
    #pragma unroll
    for (int ni = 0; ni < 4; ++ni) bv[ni] = Bf[(wn * 64 + ni * 16 + rl) * 4 + kb];
    #pragma unroll
    for (int mi = 0; mi < 4; ++mi)
      #pragma unroll
      for (int ni = 0; ni < 4; ++ni)
        acc[mi][ni] = __builtin_amdgcn_mfma_f32_16x16x32_bf16(av[mi], bv[ni], acc[mi][ni], 0, 0, 0);
    __syncthreads();
  }

  const int rb = (lane >> 4) * 4;
  #pragma unroll
  for (int mi = 0; mi < 4; ++mi)
    #pragma unroll
    for (int ni = 0; ni < 4; ++ni) {
      int mbase = m0 + wm * 64 + mi * 16 + rb;
      int col   = n0 + wn * 64 + ni * 16 + rl;
      int gate = col >> 9, kg = col & 511;
      int tt = mbase >> 5, bb0 = mbase & 31;
      float bb = bih[col] + bhh[col];
      #pragma unroll
      for (int j = 0; j < 4; ++j)
        preA3[(((size_t)tt * 512 + kg) * 32 + bb0 + j) * 4 + gate] = f2bf(acc[mi][ni][j] + bb);
    }
}

// ---------------- preA3[t=0][kg][:][gate] += (out0 - h0) @ W2^T  (row r = grow)
__global__ __launch_bounds__(256) void delta0_kernel(const float* __restrict__ Wih,
                                                     const float* __restrict__ out0,
                                                     const float* __restrict__ h0,
                                                     unsigned short* __restrict__ preA3) {
  const int r = blockIdx.x;
  const int tid = threadIdx.x;
  const int b = tid >> 3, seg = tid & 7;
  __shared__ float red[32][9];
  const float4* o4 = (const float4*)(out0 + (size_t)b * 512 + seg * 64);
  const float4* h4 = (const float4*)(h0 + (size_t)b * 512 + seg * 64);
  const float4* w4 = (const float4*)(Wih + (size_t)r * 1024 + 512 + seg * 64);
  float s = 0.f;
  #pragma unroll
  for (int j = 0; j < 16; ++j) {
    float4 o = o4[j], h = h4[j], w = w4[j];
    s += (o.x - h.x) * w.x + (o.y - h.y) * w.y + (o.z - h.z) * w.z + (o.w - h.w) * w.w;
  }
  red[b][seg] = s;
  __syncthreads();
  if (tid < 32) {
    float t = 0.f;
    #pragma unroll
    for (int j = 0; j < 8; ++j) t += red[tid][j];
    int gate = r >> 9, kgl = r & 511;
    unsigned short* p = preA3 + ((size_t)kgl * 32 + tid) * 4 + gate;
    *p = f2bf(bf2f(*p) + t);
  }
}

// ---------------- persistent LSTM, 16 blocks x 1024 threads, ROLE-SPLIT phases.
// (unchanged from R11 - proven 501 us)
__global__ __launch_bounds__(1024) void lstm_persist_rs_kernel(
    const unsigned short* __restrict__ Wrs,
    const unsigned short* __restrict__ preA3,
    const float* __restrict__ c0,
    unsigned short* __restrict__ hb0,
    unsigned short* __restrict__ hb1,
    unsigned short* __restrict__ Abf,
    unsigned int* __restrict__ flags)
{
  __shared__ unsigned short wlds[128 * 512];
  __shared__ __align__(16) char hexch[2][16 * 1024];
  const int tid = threadIdx.x, bid = blockIdx.x;
  const int lane = tid & 63, wid = tid >> 6;

  #pragma unroll
  for (int it = 0; it < 8; ++it) {
    int r = it * 16 + wid;
    const unsigned short* src = Wrs + ((size_t)bid * 128 + r) * 512 + lane * 8;
    __builtin_amdgcn_global_load_lds((const AS1 void*)src, (AS3 void*)&wlds[r * 512], 16, 0, 0);
  }

  const int myhalf = wid >> 3;
  const int rt = wid & 7;
  const int q = lane >> 4, rl = lane & 15;
  const int kg = bid * 32 + rt * 4 + q;
  const int b = myhalf * 16 + rl;
  float c_reg = c0[(size_t)b * 512 + kg];

  const int row = rt * 16 + rl;
  const char* wbase = (const char*)wlds + row * 1024;
  const int rx = (row & 7) << 4;
  const int hx = (rl & 7) << 4;

  const int sw = wid & 7;
  const int sr = sw * 2 + (lane >> 5);
  const int sc = lane & 31;
  const int sblk = sc >> 1;
  const int srx = (sr & 7) << 4;
  const int sofs = sc * 32;

  if (myhalf == 0) {
    const unsigned long long* src =
        (const unsigned long long*)(hb0 + (size_t)sr * 512) + sc * 4;
    unsigned long long d0 = ald64(src + 0), d1 = ald64(src + 1);
    unsigned long long d2 = ald64(src + 2), d3 = ald64(src + 3);
    char* dst = hexch[0] + sr * 1024;
    u64x2 w0; w0[0] = d0; w0[1] = d1;
    u64x2 w1; w1[0] = d2; w1[1] = d3;
    *(u64x2*)(dst + (sofs ^ srx)) = w0;
    *(u64x2*)(dst + ((sofs + 16) ^ srx)) = w1;
  }
  __syncthreads();

  for (int p = 0; p < 2 * T_; ++p) {
    const int t = p >> 1, ph = p & 1, buf = p & 1;

    if (myhalf == ph) {
      unsigned long long pre =
          *(const unsigned long long*)(preA3 + (((size_t)t * 512 + kg) * 32 + b) * 4);
      const char* hbase = hexch[buf] + rl * 1024;
      f32x4 acc = {}, acc2 = {};
      #pragma unroll
      for (int kk = 0; kk < 16; kk += 2) {
        int k0 = kk * 32 + q * 8;
        int k1 = k0 + 32;
        bf16x8 av0 = *(const bf16x8*)(wbase + ((k0 * 2) ^ rx));
        bf16x8 bv0 = *(const bf16x8*)(hbase + ((k0 * 2) ^ hx));
        bf16x8 av1 = *(const bf16x8*)(wbase + ((k1 * 2) ^ rx));
        bf16x8 bv1 = *(const bf16x8*)(hbase + ((k1 * 2) ^ hx));
        acc  = __builtin_amdgcn_mfma_f32_16x16x32_bf16(av0, bv0, acc, 0, 0, 0);
        acc2 = __builtin_amdgcn_mfma_f32_16x16x32_bf16(av1, bv1, acc2, 0, 0, 0);
      }
      float g0 = acc[0] + acc2[0] + bf2f((unsigned short)(pre));
      float g1 = acc[1] + acc2[1] + bf2f((unsigned short)(pre >> 16));
      float g2 = acc[2] + acc2[2] + bf2f((unsigned short)(pre >> 32));
      float g3 = acc[3] + acc2[3] + bf2f((unsigned short)(pre >> 48));
      float iv = sigm(g0), fv = sigm(g1), gv = tanh_fast(g2), ov = sigm(g3);
      float cn = fv * c_reg + iv * gv;
      c_reg = cn;
      float hn = ov * tanh_fast(cn);
      int hv = (int)f2bf(hn);
      int nb = __shfl(hv, lane + 16);
      if ((q & 1) == 0) {
        unsigned pair = (unsigned)hv | ((unsigned)nb << 16);
        if (t != T_ - 1) {
          unsigned short* hout = ((t + 1) & 1) ? hb1 : hb0;
          __hip_atomic_store((unsigned int*)(hout + (size_t)b * 512 + kg), pair,
                             __ATOMIC_RELAXED, __HIP_MEMORY_SCOPE_AGENT);
        }
        *(unsigned*)(Abf + ((size_t)b * T_ + t) * 512 + kg) = pair;
      }
    } else if (p + 1 < 2 * T_) {
      const int t2 = (p + 1) >> 1;
      if (t2 > 0) {
        const unsigned* fl = &flags[(myhalf * 16 + sblk) * 16];
        unsigned spins = 0;
        while (ald32(fl) < (unsigned)t2) {
          if (++spins > 1000000u) break;
        }
      }
      const unsigned short* hsrc = (t2 & 1) ? hb1 : hb0;
      const unsigned long long* src =
          (const unsigned long long*)(hsrc + (size_t)(myhalf * 16 + sr) * 512) + sc * 4;
      unsigned long long d0 = ald64(src + 0), d1 = ald64(src + 1);
      unsigned long long d2 = ald64(src + 2), d3 = ald64(src + 3);
      char* dst = hexch[buf ^ 1] + sr * 1024;
      u64x2 w0; w0[0] = d0; w0[1] = d1;
      u64x2 w1; w1[0] = d2; w1[1] = d3;
      *(u64x2*)(dst + (sofs ^ srx)) = w0;
      *(u64x2*)(dst + ((sofs + 16) ^ srx)) = w1;
    }

    __syncthreads();

    if (tid == ph * 512)
      __hip_atomic_store(&flags[(ph * 16 + bid) * 16], (unsigned)(t + 1),
                         __ATOMIC_RELAXED, __HIP_MEMORY_SCOPE_AGENT);
  }
}

// ---------------- projection GEMM chunk (swizzled LDS) + softmax partials
// rows [row0, row0+128*gridDim.x). use_bf=1: cached bf16 stores to Cbf
// (chunk-relative, MALL-resident for the finish pass); else f32 nt to C.
__global__ __launch_bounds__(256) void gemm_kernel(
    const unsigned short* __restrict__ A,
    const unsigned short* __restrict__ Bm,
    float* __restrict__ C,
    unsigned short* __restrict__ Cbf,
    int row0, int use_bf,
    float* __restrict__ pmax, float* __restrict__ psum)
{
  __shared__ unsigned short ldsA[2][128 * 32];
  __shared__ unsigned short ldsB[2][128 * 32];
  __shared__ float smax[2][128];
  __shared__ float ssum[2][128];
  const int tid = threadIdx.x;
  const int lane = tid & 63;
  const int wid = tid >> 6;
  const int wm = wid >> 1, wn = wid & 1;
  const int lm0 = blockIdx.x * 128;          // chunk-local
  const int m0 = row0 + lm0;                 // absolute
  const int n0 = blockIdx.y * 128;
  const int srow = lane >> 2;

  f32x4 acc[4][4] = {};
  const int NK = 512 / 32;

  auto stage = [&](int kk, int buf) {
    const int k0 = kk * 32;
    const int sw = (srow >> 1) & 3;
    const int gc = ((lane & 3) ^ sw) * 8;
    #pragma unroll
    for (int c = 0; c < 2; ++c) {
      const int r = wid * 32 + c * 16;
      const unsigned short* sa = A  + (size_t)(m0 + r + srow) * 512 + k0 + gc;
      const unsigned short* sb = Bm + (size_t)(n0 + r + srow) * 512 + k0 + gc;
      __builtin_amdgcn_global_load_lds((const AS1 void*)sa, (AS3 void*)&ldsA[buf][r * 32], 16, 0, 0);
      __builtin_amdgcn_global_load_lds((const AS1 void*)sb, (AS3 void*)&ldsB[buf][r * 32], 16, 0, 0);
    }
  };

  stage(0, 0);
  __syncthreads();

  const int rl = lane & 15;
  const int kb = lane >> 4;
  const int rsw = kb ^ ((rl >> 1) & 3);

  for (int kk = 0; kk < NK; ++kk) {
    const int buf = kk & 1;
    if (kk + 1 < NK) stage(kk + 1, buf ^ 1);
    const bf16x8* Af = (const bf16x8*)&ldsA[buf][0];
    const bf16x8* Bf = (const bf16x8*)&ldsB[buf][0];
    bf16x8 av[4], bv[4];
    #pragma unroll
    for (int mi = 0; mi < 4; ++mi) av[mi] = Af[(wm * 64 + mi * 16 + rl) * 4 + rsw];
    #pragma unroll
    for (int ni = 0; ni < 4; ++ni) bv[ni] = Bf[(wn * 64 + ni * 16 + rl) * 4 + rsw];
    #pragma unroll
    for (int mi = 0; mi < 4; ++mi)
      #pragma unroll
      for (int ni = 0; ni < 4; ++ni)
        acc[mi][ni] = __builtin_amdgcn_mfma_f32_16x16x32_bf16(av[mi], bv[ni], acc[mi][ni], 0, 0, 0);
    __syncthreads();
  }

  const int rb = kb * 4;
  if (use_bf) {
    #pragma unroll
    for (int mi = 0; mi < 4; ++mi)
      #pragma unroll
      for (int ni = 0; ni < 4; ++ni) {
        size_t lrow = (size_t)(lm0 + wm * 64 + mi * 16 + rb);
        size_t col = (size_t)(n0 + wn * 64 + ni * 16 + rl);
        #pragma unroll
        for (int j = 0; j < 4; ++j)
          Cbf[(lrow + j) * (size_t)V_ + col] = f2bf(acc[mi][ni][j]);   // cached -> MALL
      }
  } else {
    #pragma unroll
    for (int mi = 0; mi < 4; ++mi)
      #pragma unroll
      for (int ni = 0; ni < 4; ++ni) {
        size_t rrow = (size_t)(m0 + wm * 64 + mi * 16 + rb);
        size_t col = (size_t)(n0 + wn * 64 + ni * 16 + rl);
        #pragma unroll
        for (int j = 0; j < 4; ++j)
          __builtin_nontemporal_store(acc[mi][ni][j], &C[(rrow + j) * (size_t)V_ + col]);
      }
  }

  // ---- per-tile row max / sum-exp partials (absolute rows) ----
  float tm[4][4];
  #pragma unroll
  for (int mi = 0; mi < 4; ++mi)
    #pragma unroll
    for (int j = 0; j < 4; ++j) {
      float m = fmaxf(fmaxf(acc[mi][0][j], acc[mi][1][j]), fmaxf(acc[mi][2][j], acc[mi][3][j]));
      m = fmaxf(m, __shfl_xor(m, 1)); m = fmaxf(m, __shfl_xor(m, 2));
      m = fmaxf(m, __shfl_xor(m, 4)); m = fmaxf(m, __shfl_xor(m, 8));
      tm[mi][j] = m;
    }
  if (rl == 0) {
    #pragma unroll
    for (int mi = 0; mi < 4; ++mi)
      #pragma unroll
      for (int j = 0; j < 4; ++j)
        smax[wn][wm * 64 + mi * 16 + kb * 4 + j] = tm[mi][j];
  }
  __syncthreads();
  float ts[4][4];
  #pragma unroll
  for (int mi = 0; mi < 4; ++mi)
    #pragma unroll
    for (int j = 0; j < 4; ++j) {
      int rlocal = wm * 64 + mi * 16 + kb * 4 + j;
      float M = fmaxf(smax[0][rlocal], smax[1][rlocal]);
      float s = __expf(acc[mi][0][j] - M) + __expf(acc[mi][1][j] - M) +
                __expf(acc[mi][2][j] - M) + __expf(acc[mi][3][j] - M);
      s += __shfl_xor(s, 1); s += __shfl_xor(s, 2);
      s += __shfl_xor(s, 4); s += __shfl_xor(s, 8);
      ts[mi][j] = s;
    }
  if (rl == 0) {
    #pragma unroll
    for (int mi = 0; mi < 4; ++mi)
      #pragma unroll
      for (int j = 0; j < 4; ++j)
        ssum[wn][wm * 64 + mi * 16 + kb * 4 + j] = ts[mi][j];
  }
  __syncthreads();
  if (tid < 128) {
    float M = fmaxf(smax[0][tid], smax[1][tid]);
    float S = ssum[0][tid] + ssum[1][tid];
    pmax[(size_t)(m0 + tid) * 256 + blockIdx.y] = M;
    psum[(size_t)(m0 + tid) * 256 + blockIdx.y] = S;
  }
}

__device__ __forceinline__ float lse_from_partials(const float* pmax, const float* psum,
                                                   size_t row, int tid, int lane, int wid,
                                                   float* red) {
  float pm = (tid < 250) ? pmax[row * 256 + tid] : -INFINITY;
  float ps = (tid < 250) ? psum[row * 256 + tid] : 0.f;

  float m = pm;
  #pragma unroll
  for (int off = 32; off > 0; off >>= 1) m = fmaxf(m, __shfl_xor(m, off));
  if (lane == 0) red[wid] = m;
  __syncthreads();
  m = fmaxf(fmaxf(red[0], red[1]), fmaxf(red[2], red[3]));
  __syncthreads();

  float s = (tid < 250) ? ps * __expf(pm - m) : 0.f;
  #pragma unroll
  for (int off = 32; off > 0; off >>= 1) s += __shfl_xor(s, off);
  if (lane == 0) red[wid] = s;
  __syncthreads();
  s = red[0] + red[1] + red[2] + red[3];
  return m + logf(s);
}

// ---------------- finish (bf16 chunk path): C[row0+blk] = bf2f(Cbf[blk]) - lse
__global__ __launch_bounds__(256) void softmax_finish_bf_kernel(
    const unsigned short* __restrict__ Cbf, float* __restrict__ C, int row0,
    const float* __restrict__ pmax, const float* __restrict__ psum) {
  const size_t row = (size_t)row0 + blockIdx.x;
  const int tid = threadIdx.x, lane = tid & 63, wid = tid >> 6;
  __shared__ float red[4];
  const float lse = lse_from_partials(pmax, psum, row, tid, lane, wid, red);

  const u16x8* pb = (const u16x8*)(Cbf + (size_t)blockIdx.x * V_);
  f32x4* pf = (f32x4*)(C + row * (size_t)V_);
  for (int i = tid; i < 4000; i += 256) {     // 4000 x 8 ushorts = 32000
    u16x8 v = pb[i];
    f32x4 lo, hi;
    lo[0] = bf2f(v[0]) - lse; lo[1] = bf2f(v[1]) - lse;
    lo[2] = bf2f(v[2]) - lse; lo[3] = bf2f(v[3]) - lse;
    hi[0] = bf2f(v[4]) - lse; hi[1] = bf2f(v[5]) - lse;
    hi[2] = bf2f(v[6]) - lse; hi[3] = bf2f(v[7]) - lse;
    __builtin_nontemporal_store(lo, &pf[i * 2]);
    __builtin_nontemporal_store(hi, &pf[i * 2 + 1]);
  }
}

// ---------------- finish (f32 fallback): C[row] -= lse in place
__global__ __launch_bounds__(256) void softmax_finish_kernel(
    float* __restrict__ C, const float* __restrict__ pmax, const float* __restrict__ psum) {
  const size_t row = blockIdx.x;
  const int tid = threadIdx.x, lane = tid & 63, wid = tid >> 6;
  __shared__ float red[4];
  const float lse = lse_from_partials(pmax, psum, row, tid, lane, wid, red);

  f32x4* p4 = (f32x4*)(C + row * (size_t)V_);
  for (int i = tid; i < 8000; i += 256) {
    f32x4 v = p4[i];
    v -= lse;
    __builtin_nontemporal_store(v, &p4[i]);
  }
}

extern "C" void kernel_launch(void* const* d_in, const int* in_sizes, int n_in,
                              void* d_out, int out_size, void* d_ws, size_t ws_size,
                              hipStream_t stream) {
  const int*   dst  = (const int*)d_in[0];
  const float* E    = (const float*)d_in[1];
  const float* Wih  = (const float*)d_in[2];
  const float* Whh  = (const float*)d_in[3];
  const float* bih  = (const float*)d_in[4];
  const float* bhh  = (const float*)d_in[5];
  const float* h0   = (const float*)d_in[6];
  const float* c0   = (const float*)d_in[7];
  const float* out0 = (const float*)d_in[8];
  float* C = (float*)d_out;

  char* ws = (char*)d_ws;
  unsigned short* Ebf   = (unsigned short*)(ws);                      // 32.77 MB
  unsigned short* preA3 = (unsigned short*)(ws + (size_t)33554432);   // 16.78 MB
  unsigned short* Wrs   = (unsigned short*)(ws + (size_t)50331648);   // 2.10 MB
  unsigned short* embbf = (unsigned short*)(ws + (size_t)52428800);   // pre-phase
  float*          pmax  = (float*)(ws + (size_t)52428800);            // post-phase 4.19 MB
  unsigned short* W1bf  = (unsigned short*)(ws + (size_t)56623104);   // pre-phase
  float*          psum  = (float*)(ws + (size_t)56623104);            // post-phase 4.19 MB
  unsigned short* Abf   = (unsigned short*)(ws + (size_t)60817408);   // 4.19 MB
  unsigned short* hb0   = (unsigned short*)(ws + (size_t)65011712);   // 32 KB
  unsigned short* hb1   = (unsigned short*)(ws + (size_t)65044480);   // 32 KB
  unsigned int*   flg   = (unsigned int*)(ws + (size_t)65077248);     // 2 KB
  const size_t cbf_off  = 65079296;
  unsigned short* Cbf   = (unsigned short*)(ws + cbf_off);

  // pick largest chunk that fits the workspace
  const size_t avail = (ws_size > cbf_off) ? ws_size - cbf_off : 0;
  int chunk = 0;
  if      (avail >= (size_t)2048 * V_ * 2) chunk = 2048;   // 131.1 MB
  else if (avail >= (size_t)1024 * V_ * 2) chunk = 1024;   //  65.5 MB
  else if (avail >= (size_t)512  * V_ * 2) chunk = 512;    //  32.8 MB

  (void)hipMemsetAsync(flg, 0, 2048, stream);

  // --- precompute ---
  embed_bf_kernel<<<dim3(T_ * B_), dim3(64), 0, stream>>>(dst, E, embbf);
  cvt_kernel<<<dim3(2048), dim3(256), 0, stream>>>(E, Ebf, V_ * D_ / 4);
  cvt_w1_kernel<<<dim3(256), dim3(256), 0, stream>>>(Wih, W1bf, 2048 * 512 / 4);
  wr_prep_swz_kernel<<<dim3(256), dim3(256), 0, stream>>>(Wih, Whh, Wrs, 2048 * 512 / 4);

  gemm_pre_kernel<<<dim3(2048 / 128, 4096 / 128), dim3(256), 0, stream>>>(embbf, W1bf, bih, bhh, preA3);
  delta0_kernel<<<dim3(2048), dim3(256), 0, stream>>>(Wih, out0, h0, preA3);
  cvt_kernel<<<dim3(16), dim3(256), 0, stream>>>(h0, hb0, B_ * H_ / 4);

  // --- full recurrence, one launch, 16 blocks, role-split phases ---
  lstm_persist_rs_kernel<<<dim3(16), dim3(1024), 0, stream>>>(Wrs, preA3, c0, hb0, hb1, Abf, flg);

  // --- projection + fused softmax, chunked bf16 intermediate if ws allows ---
  if (chunk) {
    for (int r0 = 0; r0 < B_ * T_; r0 += chunk) {
      gemm_kernel<<<dim3(chunk / 128, V_ / 128), dim3(256), 0, stream>>>(
          Abf, Ebf, C, Cbf, r0, 1, pmax, psum);
      softmax_finish_bf_kernel<<<dim3(chunk), dim3(256), 0, stream>>>(
          Cbf, C, r0, pmax, psum);
    }
  } else {
    gemm_kernel<<<dim3((B_ * T_) / 128, V_ / 128), dim3(256), 0, stream>>>(
        Abf, Ebf, C, Cbf, 0, 0, pmax, psum);
    softmax_finish_kernel<<<dim3(B_ * T_), dim3(256), 0, stream>>>(C, pmax, psum);
  }
}

// Round 14
// 989.196 us; speedup vs baseline: 1.1202x; 1.1160x over previous
//
#include <hip/hip_runtime.h>
#include <hip/hip_bf16.h>
#include <math.h>

#define B_ 32
#define T_ 128
#define V_ 32000
#define D_ 512
#define H_ 512

typedef __attribute__((ext_vector_type(8))) short bf16x8;
typedef __attribute__((ext_vector_type(4))) float f32x4;
typedef __attribute__((ext_vector_type(2))) unsigned long long u64x2;

#define AS1 __attribute__((address_space(1)))
#define AS3 __attribute__((address_space(3)))

__device__ __forceinline__ unsigned short f2bf(float x) {
  unsigned int b = __float_as_uint(x);
  return (unsigned short)((b + 0x7FFFu + ((b >> 16) & 1u)) >> 16);
}
__device__ __forceinline__ float bf2f(unsigned short u) {
  return __uint_as_float(((unsigned int)u) << 16);
}
__device__ __forceinline__ float sigm(float x) { return 1.0f / (1.0f + __expf(-x)); }
__device__ __forceinline__ float tanh_fast(float x) { return 1.0f - 2.0f / (__expf(2.0f * x) + 1.0f); }

__device__ __forceinline__ unsigned long long ald64(const unsigned long long* p) {
  return __hip_atomic_load(p, __ATOMIC_RELAXED, __HIP_MEMORY_SCOPE_AGENT);
}
__device__ __forceinline__ unsigned ald32(const unsigned* p) {
  return __hip_atomic_load(p, __ATOMIC_RELAXED, __HIP_MEMORY_SCOPE_AGENT);
}

// ---------------- embedding gather -> bf16
__global__ __launch_bounds__(64) void embed_bf_kernel(const int* __restrict__ dst,
                                                      const float* __restrict__ E,
                                                      unsigned short* __restrict__ embbf) {
  int rt = blockIdx.x;           // t*32 + b
  int t = rt >> 5, b = rt & 31;
  int v = dst[b * T_ + t];
  const float4* src = (const float4*)(E + (size_t)v * D_);
  ushort4* d = (ushort4*)(embbf + (size_t)rt * D_);
  #pragma unroll
  for (int r = 0; r < 2; ++r) {
    float4 x = src[threadIdx.x + r * 64];
    ushort4 o; o.x = f2bf(x.x); o.y = f2bf(x.y); o.z = f2bf(x.z); o.w = f2bf(x.w);
    d[threadIdx.x + r * 64] = o;
  }
}

// ---------------- generic f32 -> bf16
__global__ void cvt_kernel(const float* __restrict__ in, unsigned short* __restrict__ out, int n4) {
  int stride = gridDim.x * blockDim.x;
  for (int i = blockIdx.x * blockDim.x + threadIdx.x; i < n4; i += stride) {
    float4 v = ((const float4*)in)[i];
    ushort4 o; o.x = f2bf(v.x); o.y = f2bf(v.y); o.z = f2bf(v.z); o.w = f2bf(v.w);
    ((ushort4*)out)[i] = o;
  }
}

// ---------------- W1bf[r][c] = bf16(Wih[r][c]), c<512 (row stride 1024)
__global__ void cvt_w1_kernel(const float* __restrict__ Wih, unsigned short* __restrict__ W1bf, int n4) {
  int stride = gridDim.x * blockDim.x;
  for (int i = blockIdx.x * blockDim.x + threadIdx.x; i < n4; i += stride) {
    int flat = i * 4;
    int r = flat >> 9, c = flat & 511;
    float4 v = *(const float4*)(Wih + (size_t)r * 1024 + c);
    ushort4 o; o.x = f2bf(v.x); o.y = f2bf(v.y); o.z = f2bf(v.z); o.w = f2bf(v.w);
    ((ushort4*)W1bf)[i] = o;
  }
}

// ---------------- Wr rows reordered for lane-local epilogue (R9 layout)
__global__ void wr_prep_swz_kernel(const float* __restrict__ Wih, const float* __restrict__ Whh,
                                   unsigned short* __restrict__ Wrs, int n4) {
  int stride = gridDim.x * blockDim.x;
  for (int i = blockIdx.x * blockDim.x + threadIdx.x; i < n4; i += stride) {
    int flat = i * 4;
    int grow = flat >> 9, k = flat & 511;
    float4 a = *(const float4*)(Wih + (size_t)grow * 1024 + 512 + k);
    float4 b = ((const float4*)Whh)[i];
    ushort4 o;
    o.x = f2bf(a.x + b.x); o.y = f2bf(a.y + b.y); o.z = f2bf(a.z + b.z); o.w = f2bf(a.w + b.w);
    int gate = grow >> 9, kgl = grow & 511;
    int orow = (kgl >> 5) * 128 + (kgl & 31) * 4 + gate;
    int chunk = (k >> 3) ^ (orow & 7);
    *(ushort4*)(Wrs + (size_t)orow * 512 + chunk * 8 + (k & 7)) = o;
  }
}

// ---------------- pre-GEMM: preA3[t][kg][b][gate] = bf16(emb . W1 + bias)
__global__ __launch_bounds__(256) void gemm_pre_kernel(
    const unsigned short* __restrict__ A,
    const unsigned short* __restrict__ Bm,
    const float* __restrict__ bih, const float* __restrict__ bhh,
    unsigned short* __restrict__ preA3)
{
  __shared__ unsigned short ldsA[2][128 * 32];
  __shared__ unsigned short ldsB[2][128 * 32];
  const int tid = threadIdx.x;
  const int lane = tid & 63;
  const int wid = tid >> 6;
  const int wm = wid >> 1, wn = wid & 1;
  const int m0 = blockIdx.y * 128;
  const int n0 = blockIdx.x * 128;
  const int srow = lane >> 2;
  const int scol = (lane & 3) * 8;

  f32x4 acc[4][4] = {};
  const int NK = 512 / 32;

  auto stage = [&](int kk, int buf) {
    const int k0 = kk * 32;
    #pragma unroll
    for (int c = 0; c < 2; ++c) {
      const int r = wid * 32 + c * 16;
      const unsigned short* sa = A  + (size_t)(m0 + r + srow) * 512 + k0 + scol;
      const unsigned short* sb = Bm + (size_t)(n0 + r + srow) * 512 + k0 + scol;
      __builtin_amdgcn_global_load_lds((const AS1 void*)sa, (AS3 void*)&ldsA[buf][r * 32], 16, 0, 0);
      __builtin_amdgcn_global_load_lds((const AS1 void*)sb, (AS3 void*)&ldsB[buf][r * 32], 16, 0, 0);
    }
  };

  stage(0, 0);
  __syncthreads();

  const int rl = lane & 15;
  const int kb = lane >> 4;

  for (int kk = 0; kk < NK; ++kk) {
    const int buf = kk & 1;
    if (kk + 1 < NK) stage(kk + 1, buf ^ 1);
    const bf16x8* Af = (const bf16x8*)&ldsA[buf][0];
    const bf16x8* Bf = (const bf16x8*)&ldsB[buf][0];
    bf16x8 av[4], bv[4];
    #pragma unroll
    for (int mi = 0; mi < 4; ++mi) av[mi] = Af[(wm * 64 + mi * 16 + rl) * 4 + kb];
    #pragma unroll
    for (int ni = 0; ni < 4; ++ni) bv[ni] = Bf[(wn * 64 + ni * 16 + rl) * 4 + kb];
    #pragma unroll
    for (int mi = 0; mi < 4; ++mi)
      #pragma unroll
      for (int ni = 0; ni < 4; ++ni)
        acc[mi][ni] = __builtin_amdgcn_mfma_f32_16x16x32_bf16(av[mi], bv[ni], acc[mi][ni], 0, 0, 0);
    __syncthreads();
  }

  const int rb = (lane >> 4) * 4;
  #pragma unroll
  for (int mi = 0; mi < 4; ++mi)
    #pragma unroll
    for (int ni = 0; ni < 4; ++ni) {
      int mbase = m0 + wm * 64 + mi * 16 + rb;
      int col   = n0 + wn * 64 + ni * 16 + rl;
      int gate = col >> 9, kg = col & 511;
      int tt = mbase >> 5, bb0 = mbase & 31;
      float bb = bih[col] + bhh[col];
      #pragma unroll
      for (int j = 0; j < 4; ++j)
        preA3[(((size_t)tt * 512 + kg) * 32 + bb0 + j) * 4 + gate] = f2bf(acc[mi][ni][j] + bb);
    }
}

// ---------------- preA3[t=0][kg][:][gate] += (out0 - h0) @ W2^T
__global__ __launch_bounds__(256) void delta0_kernel(const float* __restrict__ Wih,
                                                     const float* __restrict__ out0,
                                                     const float* __restrict__ h0,
                                                     unsigned short* __restrict__ preA3) {
  const int r = blockIdx.x;
  const int tid = threadIdx.x;
  const int b = tid >> 3, seg = tid & 7;
  __shared__ float red[32][9];
  const float4* o4 = (const float4*)(out0 + (size_t)b * 512 + seg * 64);
  const float4* h4 = (const float4*)(h0 + (size_t)b * 512 + seg * 64);
  const float4* w4 = (const float4*)(Wih + (size_t)r * 1024 + 512 + seg * 64);
  float s = 0.f;
  #pragma unroll
  for (int j = 0; j < 16; ++j) {
    float4 o = o4[j], h = h4[j], w = w4[j];
    s += (o.x - h.x) * w.x + (o.y - h.y) * w.y + (o.z - h.z) * w.z + (o.w - h.w) * w.w;
  }
  red[b][seg] = s;
  __syncthreads();
  if (tid < 32) {
    float t = 0.f;
    #pragma unroll
    for (int j = 0; j < 8; ++j) t += red[tid][j];
    int gate = r >> 9, kgl = r & 511;
    unsigned short* p = preA3 + ((size_t)kgl * 32 + tid) * 4 + gate;
    *p = f2bf(bf2f(*p) + t);
  }
}

// ---------------- MEGA: blocks 0-15 recurrence (R11 role-split, Abf->[t][b]);
// blocks 16+ projection (256x128 tile, gated on step flags, agent A loads).
__global__ __launch_bounds__(1024) void mega_kernel(
    const unsigned short* __restrict__ Wrs,
    const unsigned short* __restrict__ preA3,
    const float* __restrict__ c0,
    unsigned short* __restrict__ hb0,
    unsigned short* __restrict__ hb1,
    unsigned short* __restrict__ Abf,          // [T][B][512] bf16
    unsigned int* __restrict__ flags,          // [2][16] x 64B lines
    const unsigned short* __restrict__ Ebf,    // [V][512] bf16
    float* __restrict__ C,
    float* __restrict__ pmax, float* __restrict__ psum)
{
  __shared__ __align__(16) char smem[163840];
  const int tid = threadIdx.x, bid = blockIdx.x;
  const int lane = tid & 63, wid = tid >> 6;

  if (bid < 16) {
    // ================= RECURRENCE (R11 proven structure) =================
    unsigned short* wlds = (unsigned short*)smem;           // 128 KB
    char* hx = smem + 131072;                               // 2 x 16 KB

    #pragma unroll
    for (int it = 0; it < 8; ++it) {
      int r = it * 16 + wid;
      const unsigned short* src = Wrs + ((size_t)bid * 128 + r) * 512 + lane * 8;
      __builtin_amdgcn_global_load_lds((const AS1 void*)src, (AS3 void*)&wlds[r * 512], 16, 0, 0);
    }

    const int myhalf = wid >> 3;
    const int rt = wid & 7;
    const int q = lane >> 4, rl = lane & 15;
    const int kg = bid * 32 + rt * 4 + q;
    const int b = myhalf * 16 + rl;
    float c_reg = c0[(size_t)b * 512 + kg];

    const int row = rt * 16 + rl;
    const char* wbase = (const char*)wlds + row * 1024;
    const int rx = (row & 7) << 4;
    const int hxs = (rl & 7) << 4;

    const int sw = wid & 7;
    const int sr = sw * 2 + (lane >> 5);
    const int sc = lane & 31;
    const int sblk = sc >> 1;
    const int srx = (sr & 7) << 4;
    const int sofs = sc * 32;

    if (myhalf == 0) {
      const unsigned long long* src =
          (const unsigned long long*)(hb0 + (size_t)sr * 512) + sc * 4;
      unsigned long long d0 = ald64(src + 0), d1 = ald64(src + 1);
      unsigned long long d2 = ald64(src + 2), d3 = ald64(src + 3);
      char* dst = hx + sr * 1024;
      u64x2 w0; w0[0] = d0; w0[1] = d1;
      u64x2 w1; w1[0] = d2; w1[1] = d3;
      *(u64x2*)(dst + (sofs ^ srx)) = w0;
      *(u64x2*)(dst + ((sofs + 16) ^ srx)) = w1;
    }
    __syncthreads();

    for (int p = 0; p < 2 * T_; ++p) {
      const int t = p >> 1, ph = p & 1, buf = p & 1;

      if (myhalf == ph) {
        unsigned long long pre =
            *(const unsigned long long*)(preA3 + (((size_t)t * 512 + kg) * 32 + b) * 4);
        const char* hbase = hx + buf * 16384 + rl * 1024;
        f32x4 acc = {}, acc2 = {};
        #pragma unroll
        for (int kk = 0; kk < 16; kk += 2) {
          int k0 = kk * 32 + q * 8;
          int k1 = k0 + 32;
          bf16x8 av0 = *(const bf16x8*)(wbase + ((k0 * 2) ^ rx));
          bf16x8 bv0 = *(const bf16x8*)(hbase + ((k0 * 2) ^ hxs));
          bf16x8 av1 = *(const bf16x8*)(wbase + ((k1 * 2) ^ rx));
          bf16x8 bv1 = *(const bf16x8*)(hbase + ((k1 * 2) ^ hxs));
          acc  = __builtin_amdgcn_mfma_f32_16x16x32_bf16(av0, bv0, acc, 0, 0, 0);
          acc2 = __builtin_amdgcn_mfma_f32_16x16x32_bf16(av1, bv1, acc2, 0, 0, 0);
        }
        float g0 = acc[0] + acc2[0] + bf2f((unsigned short)(pre));
        float g1 = acc[1] + acc2[1] + bf2f((unsigned short)(pre >> 16));
        float g2 = acc[2] + acc2[2] + bf2f((unsigned short)(pre >> 32));
        float g3 = acc[3] + acc2[3] + bf2f((unsigned short)(pre >> 48));
        float iv = sigm(g0), fv = sigm(g1), gv = tanh_fast(g2), ov = sigm(g3);
        float cn = fv * c_reg + iv * gv;
        c_reg = cn;
        float hn = ov * tanh_fast(cn);
        int hv = (int)f2bf(hn);
        int nb = __shfl(hv, lane + 16);
        if ((q & 1) == 0) {
          unsigned pair = (unsigned)hv | ((unsigned)nb << 16);
          if (t != T_ - 1) {
            unsigned short* hout = ((t + 1) & 1) ? hb1 : hb0;
            __hip_atomic_store((unsigned int*)(hout + (size_t)b * 512 + kg), pair,
                               __ATOMIC_RELAXED, __HIP_MEMORY_SCOPE_AGENT);
          }
          // publish A in [t][b] layout (agent store -> MALL, read by proj blocks)
          __hip_atomic_store((unsigned int*)(Abf + ((size_t)t * 32 + b) * 512 + kg), pair,
                             __ATOMIC_RELAXED, __HIP_MEMORY_SCOPE_AGENT);
        }
      } else if (p + 1 < 2 * T_) {
        const int t2 = (p + 1) >> 1;
        if (t2 > 0) {
          const unsigned* fl = &flags[(myhalf * 16 + sblk) * 16];
          unsigned spins = 0;
          while (ald32(fl) < (unsigned)t2) {
            if (++spins > 1000000u) break;
          }
        }
        const unsigned short* hsrc = (t2 & 1) ? hb1 : hb0;
        const unsigned long long* src =
            (const unsigned long long*)(hsrc + (size_t)(myhalf * 16 + sr) * 512) + sc * 4;
        unsigned long long d0 = ald64(src + 0), d1 = ald64(src + 1);
        unsigned long long d2 = ald64(src + 2), d3 = ald64(src + 3);
        char* dst = hx + (buf ^ 1) * 16384 + sr * 1024;
        u64x2 w0; w0[0] = d0; w0[1] = d1;
        u64x2 w1; w1[0] = d2; w1[1] = d3;
        *(u64x2*)(dst + (sofs ^ srx)) = w0;
        *(u64x2*)(dst + ((sofs + 16) ^ srx)) = w1;
      }

      __syncthreads();   // publishes drained (vmcnt 0) + LDS stage visible

      if (tid == ph * 512)
        __hip_atomic_store(&flags[(ph * 16 + bid) * 16], (unsigned)(t + 1),
                           __ATOMIC_RELAXED, __HIP_MEMORY_SCOPE_AGENT);
    }
    return;
  }

  // ================= PROJECTION (gated on recurrence flags) =================
  const int e = bid - 16;
  const int n_t = e % 250, m_t = e / 250;
  const int m0 = m_t * 256, n0 = n_t * 128;

  // gate: all 32 producer flag lines must reach 8*m_t + 8
  if (tid < 32) {
    const unsigned want = (unsigned)(8 * m_t + 8);
    unsigned spins = 0;
    while (ald32(&flags[tid * 16]) < want) {
      __builtin_amdgcn_s_sleep(2);
      if (++spins > 2000000u) break;   // bailout: fail validation, don't hang
    }
  }
  __syncthreads();

  // LDS layout (rows padded to 80 B -> 2-way bank access, no swizzle)
  unsigned short* Al[2] = { (unsigned short*)smem, (unsigned short*)(smem + 20480) };
  unsigned short* Bb[2] = { (unsigned short*)(smem + 40960), (unsigned short*)(smem + 51200) };
  float (*smax)[256] = (float (*)[256])(smem + 61440);
  float (*ssum)[256] = (float (*)[256])(smem + 65536);

  const int trow = tid >> 2, tcol = tid & 3;
  const int wm = wid >> 2, wn = wid & 3;
  const int rl = lane & 15, kb = lane >> 4;

  auto stageP = [&](int kk, int bf) {
    {  // A: agent loads (coherent with producer publishes), 16B/thread
      const unsigned long long* src =
          (const unsigned long long*)(Abf + (size_t)(m0 + trow) * 512 + kk * 32 + tcol * 8);
      unsigned long long d0 = ald64(src), d1 = ald64(src + 1);
      u64x2 w; w[0] = d0; w[1] = d1;
      *(u64x2*)((char*)Al[bf] + trow * 80 + tcol * 16) = w;
    }
    if (tid < 512) {  // B: cached loads, 16B/thread
      int br = tid >> 2, bc = tid & 3;
      u64x2 w = *(const u64x2*)(Ebf + (size_t)(n0 + br) * 512 + kk * 32 + bc * 8);
      *(u64x2*)((char*)Bb[bf] + br * 80 + bc * 16) = w;
    }
  };

  f32x4 acc[4][2] = {};
  stageP(0, 0);
  __syncthreads();

  for (int kk = 0; kk < 16; ++kk) {
    const int bf = kk & 1;
    if (kk + 1 < 16) stageP(kk + 1, bf ^ 1);
    bf16x8 bv[2];
    #pragma unroll
    for (int y = 0; y < 2; ++y) {
      int br = wn * 32 + y * 16 + rl;
      bv[y] = *(const bf16x8*)((char*)Bb[bf] + br * 80 + kb * 16);
    }
    #pragma unroll
    for (int x = 0; x < 4; ++x) {
      int ar = wm * 64 + x * 16 + rl;
      bf16x8 av = *(const bf16x8*)((char*)Al[bf] + ar * 80 + kb * 16);
      #pragma unroll
      for (int y = 0; y < 2; ++y)
        acc[x][y] = __builtin_amdgcn_mfma_f32_16x16x32_bf16(av, bv[y], acc[x][y], 0, 0, 0);
    }
    __syncthreads();
  }

  // C store: arow = t*32+b -> output row b*T+t
  #pragma unroll
  for (int x = 0; x < 4; ++x)
    #pragma unroll
    for (int y = 0; y < 2; ++y) {
      int col = n0 + wn * 32 + y * 16 + rl;
      #pragma unroll
      for (int j = 0; j < 4; ++j) {
        int arow = m0 + wm * 64 + x * 16 + kb * 4 + j;
        size_t crow = (size_t)(arow & 31) * T_ + (arow >> 5);
        __builtin_nontemporal_store(acc[x][y][j], &C[crow * (size_t)V_ + col]);
      }
    }

  // partials (indexed by arow)
  #pragma unroll
  for (int x = 0; x < 4; ++x)
    #pragma unroll
    for (int j = 0; j < 4; ++j) {
      float m = fmaxf(acc[x][0][j], acc[x][1][j]);
      m = fmaxf(m, __shfl_xor(m, 1)); m = fmaxf(m, __shfl_xor(m, 2));
      m = fmaxf(m, __shfl_xor(m, 4)); m = fmaxf(m, __shfl_xor(m, 8));
      if (rl == 0) smax[wn][wm * 64 + x * 16 + kb * 4 + j] = m;
    }
  __syncthreads();
  #pragma unroll
  for (int x = 0; x < 4; ++x)
    #pragma unroll
    for (int j = 0; j < 4; ++j) {
      int rowl = wm * 64 + x * 16 + kb * 4 + j;
      float M = fmaxf(fmaxf(smax[0][rowl], smax[1][rowl]),
                      fmaxf(smax[2][rowl], smax[3][rowl]));
      float s = __expf(acc[x][0][j] - M) + __expf(acc[x][1][j] - M);
      s += __shfl_xor(s, 1); s += __shfl_xor(s, 2);
      s += __shfl_xor(s, 4); s += __shfl_xor(s, 8);
      if (rl == 0) ssum[wn][rowl] = s;
    }
  __syncthreads();
  if (tid < 256) {
    float M = fmaxf(fmaxf(smax[0][tid], smax[1][tid]),
                    fmaxf(smax[2][tid], smax[3][tid]));
    float S = ssum[0][tid] + ssum[1][tid] + ssum[2][tid] + ssum[3][tid];
    pmax[(size_t)(m0 + tid) * 256 + n_t] = M;
    psum[(size_t)(m0 + tid) * 256 + n_t] = S;
  }
}

// ---------------- finish: lse from partials (arow-indexed), C[row] -= lse
__global__ __launch_bounds__(256) void softmax_finish_kernel(
    float* __restrict__ C, const float* __restrict__ pmax, const float* __restrict__ psum) {
  const size_t row = blockIdx.x;             // output row b*T+t
  const int b = blockIdx.x >> 7, t = blockIdx.x & 127;
  const size_t arow = (size_t)t * 32 + b;
  const int tid = threadIdx.x, lane = tid & 63, wid = tid >> 6;
  __shared__ float red[4];

  float pm = (tid < 250) ? pmax[arow * 256 + tid] : -INFINITY;
  float ps = (tid < 250) ? psum[arow * 256 + tid] : 0.f;

  float m = pm;
  #pragma unroll
  for (int off = 32; off > 0; off >>= 1) m = fmaxf(m, __shfl_xor(m, off));
  if (lane == 0) red[wid] = m;
  __syncthreads();
  m = fmaxf(fmaxf(red[0], red[1]), fmaxf(red[2], red[3]));
  __syncthreads();

  float s = (tid < 250) ? ps * __expf(pm - m) : 0.f;
  #pragma unroll
  for (int off = 32; off > 0; off >>= 1) s += __shfl_xor(s, off);
  if (lane == 0) red[wid] = s;
  __syncthreads();
  s = red[0] + red[1] + red[2] + red[3];
  const float lse = m + logf(s);

  f32x4* p4 = (f32x4*)(C + row * (size_t)V_);
  for (int i = tid; i < 8000; i += 256) {
    f32x4 v = p4[i];
    v -= lse;
    __builtin_nontemporal_store(v, &p4[i]);
  }
}

extern "C" void kernel_launch(void* const* d_in, const int* in_sizes, int n_in,
                              void* d_out, int out_size, void* d_ws, size_t ws_size,
                              hipStream_t stream) {
  const int*   dst  = (const int*)d_in[0];
  const float* E    = (const float*)d_in[1];
  const float* Wih  = (const float*)d_in[2];
  const float* Whh  = (const float*)d_in[3];
  const float* bih  = (const float*)d_in[4];
  const float* bhh  = (const float*)d_in[5];
  const float* h0   = (const float*)d_in[6];
  const float* c0   = (const float*)d_in[7];
  const float* out0 = (const float*)d_in[8];
  float* C = (float*)d_out;

  char* ws = (char*)d_ws;
  unsigned short* Ebf   = (unsigned short*)(ws);                      // 32.77 MB
  unsigned short* preA3 = (unsigned short*)(ws + (size_t)33554432);   // 16.78 MB
  unsigned short* Wrs   = (unsigned short*)(ws + (size_t)50331648);   // 2.10 MB
  unsigned short* embbf = (unsigned short*)(ws + (size_t)52428800);   // pre-phase
  float*          pmax  = (float*)(ws + (size_t)52428800);            // post-phase 4.19 MB
  unsigned short* W1bf  = (unsigned short*)(ws + (size_t)56623104);   // pre-phase
  float*          psum  = (float*)(ws + (size_t)56623104);            // post-phase 4.19 MB
  unsigned short* Abf   = (unsigned short*)(ws + (size_t)60817408);   // 4.19 MB
  unsigned short* hb0   = (unsigned short*)(ws + (size_t)65011712);   // 32 KB
  unsigned short* hb1   = (unsigned short*)(ws + (size_t)65044480);   // 32 KB
  unsigned int*   flg   = (unsigned int*)(ws + (size_t)65077248);     // 2 KB

  (void)hipMemsetAsync(flg, 0, 2048, stream);

  // --- precompute ---
  embed_bf_kernel<<<dim3(T_ * B_), dim3(64), 0, stream>>>(dst, E, embbf);
  cvt_kernel<<<dim3(2048), dim3(256), 0, stream>>>(E, Ebf, V_ * D_ / 4);
  cvt_w1_kernel<<<dim3(256), dim3(256), 0, stream>>>(Wih, W1bf, 2048 * 512 / 4);
  wr_prep_swz_kernel<<<dim3(256), dim3(256), 0, stream>>>(Wih, Whh, Wrs, 2048 * 512 / 4);

  gemm_pre_kernel<<<dim3(2048 / 128, 4096 / 128), dim3(256), 0, stream>>>(embbf, W1bf, bih, bhh, preA3);
  delta0_kernel<<<dim3(2048), dim3(256), 0, stream>>>(Wih, out0, h0, preA3);
  cvt_kernel<<<dim3(16), dim3(256), 0, stream>>>(h0, hb0, B_ * H_ / 4);

  // --- recurrence + overlapped projection, one launch ---
  mega_kernel<<<dim3(16 + 16 * 250), dim3(1024), 0, stream>>>(
      Wrs, preA3, c0, hb0, hb1, Abf, flg, Ebf, C, pmax, psum);

  // --- log-softmax finish ---
  softmax_finish_kernel<<<dim3(B_ * T_), dim3(256), 0, stream>>>(C, pmax, psum);
}

// Round 15
// 962.413 us; speedup vs baseline: 1.1514x; 1.0278x over previous
//
#include <hip/hip_runtime.h>
#include <hip/hip_bf16.h>
#include <math.h>

#define B_ 32
#define T_ 128
#define V_ 32000
#define D_ 512
#define H_ 512

typedef __attribute__((ext_vector_type(8))) short bf16x8;
typedef __attribute__((ext_vector_type(4))) float f32x4;
typedef __attribute__((ext_vector_type(2))) unsigned long long u64x2;

#define AS1 __attribute__((address_space(1)))
#define AS3 __attribute__((address_space(3)))

__device__ __forceinline__ unsigned short f2bf(float x) {
  unsigned int b = __float_as_uint(x);
  return (unsigned short)((b + 0x7FFFu + ((b >> 16) & 1u)) >> 16);
}
__device__ __forceinline__ float bf2f(unsigned short u) {
  return __uint_as_float(((unsigned int)u) << 16);
}
__device__ __forceinline__ float sigm(float x) { return 1.0f / (1.0f + __expf(-x)); }
__device__ __forceinline__ float tanh_fast(float x) { return 1.0f - 2.0f / (__expf(2.0f * x) + 1.0f); }

__device__ __forceinline__ unsigned long long ald64(const unsigned long long* p) {
  return __hip_atomic_load(p, __ATOMIC_RELAXED, __HIP_MEMORY_SCOPE_AGENT);
}
__device__ __forceinline__ unsigned ald32(const unsigned* p) {
  return __hip_atomic_load(p, __ATOMIC_RELAXED, __HIP_MEMORY_SCOPE_AGENT);
}

// ---------------- embedding gather -> bf16
__global__ __launch_bounds__(64) void embed_bf_kernel(const int* __restrict__ dst,
                                                      const float* __restrict__ E,
                                                      unsigned short* __restrict__ embbf) {
  int rt = blockIdx.x;           // t*32 + b
  int t = rt >> 5, b = rt & 31;
  int v = dst[b * T_ + t];
  const float4* src = (const float4*)(E + (size_t)v * D_);
  ushort4* d = (ushort4*)(embbf + (size_t)rt * D_);
  #pragma unroll
  for (int r = 0; r < 2; ++r) {
    float4 x = src[threadIdx.x + r * 64];
    ushort4 o; o.x = f2bf(x.x); o.y = f2bf(x.y); o.z = f2bf(x.z); o.w = f2bf(x.w);
    d[threadIdx.x + r * 64] = o;
  }
}

// ---------------- generic f32 -> bf16
__global__ void cvt_kernel(const float* __restrict__ in, unsigned short* __restrict__ out, int n4) {
  int stride = gridDim.x * blockDim.x;
  for (int i = blockIdx.x * blockDim.x + threadIdx.x; i < n4; i += stride) {
    float4 v = ((const float4*)in)[i];
    ushort4 o; o.x = f2bf(v.x); o.y = f2bf(v.y); o.z = f2bf(v.z); o.w = f2bf(v.w);
    ((ushort4*)out)[i] = o;
  }
}

// ---------------- W1bf[r][c] = bf16(Wih[r][c]), c<512 (row stride 1024)
__global__ void cvt_w1_kernel(const float* __restrict__ Wih, unsigned short* __restrict__ W1bf, int n4) {
  int stride = gridDim.x * blockDim.x;
  for (int i = blockIdx.x * blockDim.x + threadIdx.x; i < n4; i += stride) {
    int flat = i * 4;
    int r = flat >> 9, c = flat & 511;
    float4 v = *(const float4*)(Wih + (size_t)r * 1024 + c);
    ushort4 o; o.x = f2bf(v.x); o.y = f2bf(v.y); o.z = f2bf(v.z); o.w = f2bf(v.w);
    ((ushort4*)W1bf)[i] = o;
  }
}

// ---------------- Wr rows reordered for lane-local epilogue (R9 layout)
__global__ void wr_prep_swz_kernel(const float* __restrict__ Wih, const float* __restrict__ Whh,
                                   unsigned short* __restrict__ Wrs, int n4) {
  int stride = gridDim.x * blockDim.x;
  for (int i = blockIdx.x * blockDim.x + threadIdx.x; i < n4; i += stride) {
    int flat = i * 4;
    int grow = flat >> 9, k = flat & 511;
    float4 a = *(const float4*)(Wih + (size_t)grow * 1024 + 512 + k);
    float4 b = ((const float4*)Whh)[i];
    ushort4 o;
    o.x = f2bf(a.x + b.x); o.y = f2bf(a.y + b.y); o.z = f2bf(a.z + b.z); o.w = f2bf(a.w + b.w);
    int gate = grow >> 9, kgl = grow & 511;
    int orow = (kgl >> 5) * 128 + (kgl & 31) * 4 + gate;
    int chunk = (k >> 3) ^ (orow & 7);
    *(ushort4*)(Wrs + (size_t)orow * 512 + chunk * 8 + (k & 7)) = o;
  }
}

// ---------------- pre-GEMM: preA3[t][kg][b][gate] = bf16(emb . W1 + bias)
__global__ __launch_bounds__(256) void gemm_pre_kernel(
    const unsigned short* __restrict__ A,
    const unsigned short* __restrict__ Bm,
    const float* __restrict__ bih, const float* __restrict__ bhh,
    unsigned short* __restrict__ preA3)
{
  __shared__ unsigned short ldsA[2][128 * 32];
  __shared__ unsigned short ldsB[2][128 * 32];
  const int tid = threadIdx.x;
  const int lane = tid & 63;
  const int wid = tid >> 6;
  const int wm = wid >> 1, wn = wid & 1;
  const int m0 = blockIdx.y * 128;
  const int n0 = blockIdx.x * 128;
  const int srow = lane >> 2;
  const int scol = (lane & 3) * 8;

  f32x4 acc[4][4] = {};
  const int NK = 512 / 32;

  auto stage = [&](int kk, int buf) {
    const int k0 = kk * 32;
    #pragma unroll
    for (int c = 0; c < 2; ++c) {
      const int r = wid * 32 + c * 16;
      const unsigned short* sa = A  + (size_t)(m0 + r + srow) * 512 + k0 + scol;
      const unsigned short* sb = Bm + (size_t)(n0 + r + srow) * 512 + k0 + scol;
      __builtin_amdgcn_global_load_lds((const AS1 void*)sa, (AS3 void*)&ldsA[buf][r * 32], 16, 0, 0);
      __builtin_amdgcn_global_load_lds((const AS1 void*)sb, (AS3 void*)&ldsB[buf][r * 32], 16, 0, 0);
    }
  };

  stage(0, 0);
  __syncthreads();

  const int rl = lane & 15;
  const int kb = lane >> 4;

  for (int kk = 0; kk < NK; ++kk) {
    const int buf = kk & 1;
    if (kk + 1 < NK) stage(kk + 1, buf ^ 1);
    const bf16x8* Af = (const bf16x8*)&ldsA[buf][0];
    const bf16x8* Bf = (const bf16x8*)&ldsB[buf][0];
    bf16x8 av[4], bv[4];
    #pragma unroll
    for (int mi = 0; mi < 4; ++mi) av[mi] = Af[(wm * 64 + mi * 16 + rl) * 4 + kb];
    #pragma unroll
    for (int ni = 0; ni < 4; ++ni) bv[ni] = Bf[(wn * 64 + ni * 16 + rl) * 4 + kb];
    #pragma unroll
    for (int mi = 0; mi < 4; ++mi)
      #pragma unroll
      for (int ni = 0; ni < 4; ++ni)
        acc[mi][ni] = __builtin_amdgcn_mfma_f32_16x16x32_bf16(av[mi], bv[ni], acc[mi][ni], 0, 0, 0);
    __syncthreads();
  }

  const int rb = (lane >> 4) * 4;
  #pragma unroll
  for (int mi = 0; mi < 4; ++mi)
    #pragma unroll
    for (int ni = 0; ni < 4; ++ni) {
      int mbase = m0 + wm * 64 + mi * 16 + rb;
      int col   = n0 + wn * 64 + ni * 16 + rl;
      int gate = col >> 9, kg = col & 511;
      int tt = mbase >> 5, bb0 = mbase & 31;
      float bb = bih[col] + bhh[col];
      #pragma unroll
      for (int j = 0; j < 4; ++j)
        preA3[(((size_t)tt * 512 + kg) * 32 + bb0 + j) * 4 + gate] = f2bf(acc[mi][ni][j] + bb);
    }
}

// ---------------- preA3[t=0][kg][:][gate] += (out0 - h0) @ W2^T
__global__ __launch_bounds__(256) void delta0_kernel(const float* __restrict__ Wih,
                                                     const float* __restrict__ out0,
                                                     const float* __restrict__ h0,
                                                     unsigned short* __restrict__ preA3) {
  const int r = blockIdx.x;
  const int tid = threadIdx.x;
  const int b = tid >> 3, seg = tid & 7;
  __shared__ float red[32][9];
  const float4* o4 = (const float4*)(out0 + (size_t)b * 512 + seg * 64);
  const float4* h4 = (const float4*)(h0 + (size_t)b * 512 + seg * 64);
  const float4* w4 = (const float4*)(Wih + (size_t)r * 1024 + 512 + seg * 64);
  float s = 0.f;
  #pragma unroll
  for (int j = 0; j < 16; ++j) {
    float4 o = o4[j], h = h4[j], w = w4[j];
    s += (o.x - h.x) * w.x + (o.y - h.y) * w.y + (o.z - h.z) * w.z + (o.w - h.w) * w.w;
  }
  red[b][seg] = s;
  __syncthreads();
  if (tid < 32) {
    float t = 0.f;
    #pragma unroll
    for (int j = 0; j < 8; ++j) t += red[tid][j];
    int gate = r >> 9, kgl = r & 511;
    unsigned short* p = preA3 + ((size_t)kgl * 32 + tid) * 4 + gate;
    *p = f2bf(bf2f(*p) + t);
  }
}

// ---------------- MEGA: blocks 0-15 recurrence (R11 role-split, Abf->[t][b]);
// blocks 16+ projection (256x128, gated via drift-bound 2-line poll, cached A,
// XOR-swizzled LDS).
__global__ __launch_bounds__(1024) void mega_kernel(
    const unsigned short* __restrict__ Wrs,
    const unsigned short* __restrict__ preA3,
    const float* __restrict__ c0,
    unsigned short* __restrict__ hb0,
    unsigned short* __restrict__ hb1,
    unsigned short* __restrict__ Abf,          // [T][B][512] bf16
    unsigned int* __restrict__ flags,          // [2][16] x 64B lines
    const unsigned short* __restrict__ Ebf,    // [V][512] bf16
    float* __restrict__ C,
    float* __restrict__ pmax, float* __restrict__ psum)
{
  __shared__ __align__(16) char smem[163840];
  const int tid = threadIdx.x, bid = blockIdx.x;
  const int lane = tid & 63, wid = tid >> 6;

  if (bid < 16) {
    // ================= RECURRENCE (R11 proven structure) =================
    unsigned short* wlds = (unsigned short*)smem;           // 128 KB
    char* hx = smem + 131072;                               // 2 x 16 KB

    #pragma unroll
    for (int it = 0; it < 8; ++it) {
      int r = it * 16 + wid;
      const unsigned short* src = Wrs + ((size_t)bid * 128 + r) * 512 + lane * 8;
      __builtin_amdgcn_global_load_lds((const AS1 void*)src, (AS3 void*)&wlds[r * 512], 16, 0, 0);
    }

    const int myhalf = wid >> 3;
    const int rt = wid & 7;
    const int q = lane >> 4, rl = lane & 15;
    const int kg = bid * 32 + rt * 4 + q;
    const int b = myhalf * 16 + rl;
    float c_reg = c0[(size_t)b * 512 + kg];

    const int row = rt * 16 + rl;
    const char* wbase = (const char*)wlds + row * 1024;
    const int rx = (row & 7) << 4;
    const int hxs = (rl & 7) << 4;

    const int sw = wid & 7;
    const int sr = sw * 2 + (lane >> 5);
    const int sc = lane & 31;
    const int sblk = sc >> 1;
    const int srx = (sr & 7) << 4;
    const int sofs = sc * 32;

    if (myhalf == 0) {
      const unsigned long long* src =
          (const unsigned long long*)(hb0 + (size_t)sr * 512) + sc * 4;
      unsigned long long d0 = ald64(src + 0), d1 = ald64(src + 1);
      unsigned long long d2 = ald64(src + 2), d3 = ald64(src + 3);
      char* dst = hx + sr * 1024;
      u64x2 w0; w0[0] = d0; w0[1] = d1;
      u64x2 w1; w1[0] = d2; w1[1] = d3;
      *(u64x2*)(dst + (sofs ^ srx)) = w0;
      *(u64x2*)(dst + ((sofs + 16) ^ srx)) = w1;
    }
    __syncthreads();

    for (int p = 0; p < 2 * T_; ++p) {
      const int t = p >> 1, ph = p & 1, buf = p & 1;

      if (myhalf == ph) {
        unsigned long long pre =
            *(const unsigned long long*)(preA3 + (((size_t)t * 512 + kg) * 32 + b) * 4);
        const char* hbase = hx + buf * 16384 + rl * 1024;
        f32x4 acc = {}, acc2 = {};
        #pragma unroll
        for (int kk = 0; kk < 16; kk += 2) {
          int k0 = kk * 32 + q * 8;
          int k1 = k0 + 32;
          bf16x8 av0 = *(const bf16x8*)(wbase + ((k0 * 2) ^ rx));
          bf16x8 bv0 = *(const bf16x8*)(hbase + ((k0 * 2) ^ hxs));
          bf16x8 av1 = *(const bf16x8*)(wbase + ((k1 * 2) ^ rx));
          bf16x8 bv1 = *(const bf16x8*)(hbase + ((k1 * 2) ^ hxs));
          acc  = __builtin_amdgcn_mfma_f32_16x16x32_bf16(av0, bv0, acc, 0, 0, 0);
          acc2 = __builtin_amdgcn_mfma_f32_16x16x32_bf16(av1, bv1, acc2, 0, 0, 0);
        }
        float g0 = acc[0] + acc2[0] + bf2f((unsigned short)(pre));
        float g1 = acc[1] + acc2[1] + bf2f((unsigned short)(pre >> 16));
        float g2 = acc[2] + acc2[2] + bf2f((unsigned short)(pre >> 32));
        float g3 = acc[3] + acc2[3] + bf2f((unsigned short)(pre >> 48));
        float iv = sigm(g0), fv = sigm(g1), gv = tanh_fast(g2), ov = sigm(g3);
        float cn = fv * c_reg + iv * gv;
        c_reg = cn;
        float hn = ov * tanh_fast(cn);
        int hv = (int)f2bf(hn);
        int nb = __shfl(hv, lane + 16);
        if ((q & 1) == 0) {
          unsigned pair = (unsigned)hv | ((unsigned)nb << 16);
          if (t != T_ - 1) {
            unsigned short* hout = ((t + 1) & 1) ? hb1 : hb0;
            __hip_atomic_store((unsigned int*)(hout + (size_t)b * 512 + kg), pair,
                               __ATOMIC_RELAXED, __HIP_MEMORY_SCOPE_AGENT);
          }
          __hip_atomic_store((unsigned int*)(Abf + ((size_t)t * 32 + b) * 512 + kg), pair,
                             __ATOMIC_RELAXED, __HIP_MEMORY_SCOPE_AGENT);
        }
      } else if (p + 1 < 2 * T_) {
        const int t2 = (p + 1) >> 1;
        if (t2 > 0) {
          const unsigned* fl = &flags[(myhalf * 16 + sblk) * 16];
          unsigned spins = 0;
          while (ald32(fl) < (unsigned)t2) {
            if (++spins > 1000000u) break;
          }
        }
        const unsigned short* hsrc = (t2 & 1) ? hb1 : hb0;
        const unsigned long long* src =
            (const unsigned long long*)(hsrc + (size_t)(myhalf * 16 + sr) * 512) + sc * 4;
        unsigned long long d0 = ald64(src + 0), d1 = ald64(src + 1);
        unsigned long long d2 = ald64(src + 2), d3 = ald64(src + 3);
        char* dst = hx + (buf ^ 1) * 16384 + sr * 1024;
        u64x2 w0; w0[0] = d0; w0[1] = d1;
        u64x2 w1; w1[0] = d2; w1[1] = d3;
        *(u64x2*)(dst + (sofs ^ srx)) = w0;
        *(u64x2*)(dst + ((sofs + 16) ^ srx)) = w1;
      }

      __syncthreads();   // publishes drained (vmcnt 0) + LDS stage visible

      if (tid == ph * 512)
        __hip_atomic_store(&flags[(ph * 16 + bid) * 16], (unsigned)(t + 1),
                           __ATOMIC_RELAXED, __HIP_MEMORY_SCOPE_AGENT);
    }
    return;
  }

  // ================= PROJECTION (gated on recurrence flags) =================
  const int e = bid - 16;
  const int n_t = e % 250, m_t = e / 250;
  const int m0 = m_t * 256, n0 = n_t * 128;

  // gate (single-thread, low-contention):
  // drift bound: flags[blk0,half]=v => that block completed step v-1, whose
  // stage waited for ALL producer flags >= v-1. So both halves of block 0
  // >= want+1 implies all 32 flags >= want. Last cohort: terminal value 128.
  if (tid == 0) {
    unsigned spins = 0;
    if (m_t == 15) {
      for (int i = 0; i < 32; ++i)
        while (ald32(&flags[i * 16]) < 128u) {
          __builtin_amdgcn_s_sleep(8);
          if (++spins > 3000000u) break;
        }
    } else {
      const unsigned want1 = (unsigned)(8 * m_t + 9);
      while (ald32(&flags[0]) < want1 || ald32(&flags[256]) < want1) {
        __builtin_amdgcn_s_sleep(8);
        if (++spins > 3000000u) break;
      }
    }
  }
  __syncthreads();

  // LDS: A dbuf 2x16KB (rows 64B, 16B-chunk ^ ((row>>1)&3)), B dbuf 2x8KB, partials 8KB
  unsigned short* Al[2] = { (unsigned short*)smem, (unsigned short*)(smem + 16384) };
  unsigned short* Bb[2] = { (unsigned short*)(smem + 32768), (unsigned short*)(smem + 40960) };
  float (*smax)[256] = (float (*)[256])(smem + 49152);
  float (*ssum)[256] = (float (*)[256])(smem + 53248);

  const int trow = tid >> 2, tcol = tid & 3;
  const int wm = wid >> 2, wn = wid & 3;
  const int rl = lane & 15, kb = lane >> 4;

  auto stageP = [&](int kk, int bf) {
    {  // A: cached loads (post-gate first touch => fresh from MALL, L2-shared)
      u64x2 w = *(const u64x2*)(Abf + (size_t)(m0 + trow) * 512 + kk * 32 + tcol * 8);
      *(u64x2*)((char*)Al[bf] + trow * 64 + ((tcol ^ ((trow >> 1) & 3)) * 16)) = w;
    }
    if (tid < 512) {  // B: cached loads
      int br = tid >> 2, bc = tid & 3;
      u64x2 w = *(const u64x2*)(Ebf + (size_t)(n0 + br) * 512 + kk * 32 + bc * 8);
      *(u64x2*)((char*)Bb[bf] + br * 64 + ((bc ^ ((br >> 1) & 3)) * 16)) = w;
    }
  };

  f32x4 acc[4][2] = {};
  stageP(0, 0);
  __syncthreads();

  for (int kk = 0; kk < 16; ++kk) {
    const int bf = kk & 1;
    if (kk + 1 < 16) stageP(kk + 1, bf ^ 1);
    bf16x8 bv[2];
    #pragma unroll
    for (int y = 0; y < 2; ++y) {
      int br = wn * 32 + y * 16 + rl;
      bv[y] = *(const bf16x8*)((char*)Bb[bf] + br * 64 + ((kb ^ ((br >> 1) & 3)) * 16));
    }
    #pragma unroll
    for (int x = 0; x < 4; ++x) {
      int ar = wm * 64 + x * 16 + rl;
      bf16x8 av = *(const bf16x8*)((char*)Al[bf] + ar * 64 + ((kb ^ ((ar >> 1) & 3)) * 16));
      #pragma unroll
      for (int y = 0; y < 2; ++y)
        acc[x][y] = __builtin_amdgcn_mfma_f32_16x16x32_bf16(av, bv[y], acc[x][y], 0, 0, 0);
    }
    __syncthreads();
  }

  // C store: arow = t*32+b -> output row b*T+t
  #pragma unroll
  for (int x = 0; x < 4; ++x)
    #pragma unroll
    for (int y = 0; y < 2; ++y) {
      int col = n0 + wn * 32 + y * 16 + rl;
      #pragma unroll
      for (int j = 0; j < 4; ++j) {
        int arow = m0 + wm * 64 + x * 16 + kb * 4 + j;
        size_t crow = (size_t)(arow & 31) * T_ + (arow >> 5);
        __builtin_nontemporal_store(acc[x][y][j], &C[crow * (size_t)V_ + col]);
      }
    }

  // partials (indexed by arow)
  #pragma unroll
  for (int x = 0; x < 4; ++x)
    #pragma unroll
    for (int j = 0; j < 4; ++j) {
      float m = fmaxf(acc[x][0][j], acc[x][1][j]);
      m = fmaxf(m, __shfl_xor(m, 1)); m = fmaxf(m, __shfl_xor(m, 2));
      m = fmaxf(m, __shfl_xor(m, 4)); m = fmaxf(m, __shfl_xor(m, 8));
      if (rl == 0) smax[wn][wm * 64 + x * 16 + kb * 4 + j] = m;
    }
  __syncthreads();
  #pragma unroll
  for (int x = 0; x < 4; ++x)
    #pragma unroll
    for (int j = 0; j < 4; ++j) {
      int rowl = wm * 64 + x * 16 + kb * 4 + j;
      float M = fmaxf(fmaxf(smax[0][rowl], smax[1][rowl]),
                      fmaxf(smax[2][rowl], smax[3][rowl]));
      float s = __expf(acc[x][0][j] - M) + __expf(acc[x][1][j] - M);
      s += __shfl_xor(s, 1); s += __shfl_xor(s, 2);
      s += __shfl_xor(s, 4); s += __shfl_xor(s, 8);
      if (rl == 0) ssum[wn][rowl] = s;
    }
  __syncthreads();
  if (tid < 256) {
    float M = fmaxf(fmaxf(smax[0][tid], smax[1][tid]),
                    fmaxf(smax[2][tid], smax[3][tid]));
    float S = ssum[0][tid] + ssum[1][tid] + ssum[2][tid] + ssum[3][tid];
    pmax[(size_t)(m0 + tid) * 256 + n_t] = M;
    psum[(size_t)(m0 + tid) * 256 + n_t] = S;
  }
}

// ---------------- finish: lse from partials (arow-indexed), C[row] -= lse
__global__ __launch_bounds__(256) void softmax_finish_kernel(
    float* __restrict__ C, const float* __restrict__ pmax, const float* __restrict__ psum) {
  const size_t row = blockIdx.x;             // output row b*T+t
  const int b = blockIdx.x >> 7, t = blockIdx.x & 127;
  const size_t arow = (size_t)t * 32 + b;
  const int tid = threadIdx.x, lane = tid & 63, wid = tid >> 6;
  __shared__ float red[4];

  float pm = (tid < 250) ? pmax[arow * 256 + tid] : -INFINITY;
  float ps = (tid < 250) ? psum[arow * 256 + tid] : 0.f;

  float m = pm;
  #pragma unroll
  for (int off = 32; off > 0; off >>= 1) m = fmaxf(m, __shfl_xor(m, off));
  if (lane == 0) red[wid] = m;
  __syncthreads();
  m = fmaxf(fmaxf(red[0], red[1]), fmaxf(red[2], red[3]));
  __syncthreads();

  float s = (tid < 250) ? ps * __expf(pm - m) : 0.f;
  #pragma unroll
  for (int off = 32; off > 0; off >>= 1) s += __shfl_xor(s, off);
  if (lane == 0) red[wid] = s;
  __syncthreads();
  s = red[0] + red[1] + red[2] + red[3];
  const float lse = m + logf(s);

  f32x4* p4 = (f32x4*)(C + row * (size_t)V_);
  for (int i = tid; i < 8000; i += 256) {
    f32x4 v = p4[i];
    v -= lse;
    __builtin_nontemporal_store(v, &p4[i]);
  }
}

extern "C" void kernel_launch(void* const* d_in, const int* in_sizes, int n_in,
                              void* d_out, int out_size, void* d_ws, size_t ws_size,
                              hipStream_t stream) {
  const int*   dst  = (const int*)d_in[0];
  const float* E    = (const float*)d_in[1];
  const float* Wih  = (const float*)d_in[2];
  const float* Whh  = (const float*)d_in[3];
  const float* bih  = (const float*)d_in[4];
  const float* bhh  = (const float*)d_in[5];
  const float* h0   = (const float*)d_in[6];
  const float* c0   = (const float*)d_in[7];
  const float* out0 = (const float*)d_in[8];
  float* C = (float*)d_out;

  char* ws = (char*)d_ws;
  unsigned short* Ebf   = (unsigned short*)(ws);                      // 32.77 MB
  unsigned short* preA3 = (unsigned short*)(ws + (size_t)33554432);   // 16.78 MB
  unsigned short* Wrs   = (unsigned short*)(ws + (size_t)50331648);   // 2.10 MB
  unsigned short* embbf = (unsigned short*)(ws + (size_t)52428800);   // pre-phase
  float*          pmax  = (float*)(ws + (size_t)52428800);            // post-phase 4.19 MB
  unsigned short* W1bf  = (unsigned short*)(ws + (size_t)56623104);   // pre-phase
  float*          psum  = (float*)(ws + (size_t)56623104);            // post-phase 4.19 MB
  unsigned short* Abf   = (unsigned short*)(ws + (size_t)60817408);   // 4.19 MB
  unsigned short* hb0   = (unsigned short*)(ws + (size_t)65011712);   // 32 KB
  unsigned short* hb1   = (unsigned short*)(ws + (size_t)65044480);   // 32 KB
  unsigned int*   flg   = (unsigned int*)(ws + (size_t)65077248);     // 2 KB

  (void)hipMemsetAsync(flg, 0, 2048, stream);

  // --- precompute ---
  embed_bf_kernel<<<dim3(T_ * B_), dim3(64), 0, stream>>>(dst, E, embbf);
  cvt_kernel<<<dim3(2048), dim3(256), 0, stream>>>(E, Ebf, V_ * D_ / 4);
  cvt_w1_kernel<<<dim3(256), dim3(256), 0, stream>>>(Wih, W1bf, 2048 * 512 / 4);
  wr_prep_swz_kernel<<<dim3(256), dim3(256), 0, stream>>>(Wih, Whh, Wrs, 2048 * 512 / 4);

  gemm_pre_kernel<<<dim3(2048 / 128, 4096 / 128), dim3(256), 0, stream>>>(embbf, W1bf, bih, bhh, preA3);
  delta0_kernel<<<dim3(2048), dim3(256), 0, stream>>>(Wih, out0, h0, preA3);
  cvt_kernel<<<dim3(16), dim3(256), 0, stream>>>(h0, hb0, B_ * H_ / 4);

  // --- recurrence + overlapped projection, one launch ---
  mega_kernel<<<dim3(16 + 16 * 250), dim3(1024), 0, stream>>>(
      Wrs, preA3, c0, hb0, hb1, Abf, flg, Ebf, C, pmax, psum);

  // --- log-softmax finish ---
  softmax_finish_kernel<<<dim3(B_ * T_), dim3(256), 0, stream>>>(C, pmax, psum);
}